// Round 5
// baseline (225.075 us; speedup 1.0000x reference)
//
#include <hip/hip_runtime.h>
#include <hip/hip_bf16.h>
#include <math.h>

#define B_  512
#define DM  1024
#define DI  2048
#define DS  64
#define DTR 64
#define DT  64
#define G_  8
#define E_  4
#define DC  4

typedef __bf16 bf16x8 __attribute__((ext_vector_type(8)));
typedef float  f32x4  __attribute__((ext_vector_type(4)));
typedef unsigned short ushort_t;

__device__ __forceinline__ float bf2f(__hip_bfloat16 h) { return __bfloat162float(h); }
__device__ __forceinline__ __hip_bfloat16 f2bf(float f) { return __float2bfloat16(f); }
__device__ __forceinline__ float sigmoidf_(float x){ return 1.f/(1.f+expf(-x)); }
__device__ __forceinline__ float siluf_(float x){ return x*sigmoidf_(x); }
__device__ __forceinline__ float softplusf_(float x){ return (x>20.f)? x : log1pf(expf(x)); }

__device__ __forceinline__ unsigned int pack2(float a, float b) {
  unsigned short ua = __builtin_bit_cast(unsigned short, (__bf16)a);
  unsigned short ub = __builtin_bit_cast(unsigned short, (__bf16)b);
  return (unsigned int)ua | ((unsigned int)ub << 16);
}
__device__ __forceinline__ uint4 cvt8(float4 v0, float4 v1) {
  uint4 r;
  r.x = pack2(v0.x, v0.y); r.y = pack2(v0.z, v0.w);
  r.z = pack2(v1.x, v1.y); r.w = pack2(v1.z, v1.w);
  return r;
}

enum EpiKind { EPI_PART=0, EPI_G2=1, EPI_G4=2 };

struct KParams {
  const float *uk, *tk_c, *tk_p, *W_in, *b_in, *rW, *rb, *freq, *phase, *kanW;
  const float *W_inproj, *conv_w, *conv_b, *W_x, *W_dt, *dt_bias, *W_delta, *D_skip, *W_out;
  __hip_bfloat16 *Pu, *Xs, *Sz, *Yb, *Acat;
  __hip_bfloat16 *uk_bf, *Win_bf, *Wip_bf, *Wx_bf, *Wdt128, *Wout_bf;
  float *bc, *Part, *out_hk, *out_w, *out_mask;
};

// ---- weight/activation f32 -> bf16 pre-convert (one streaming pass) ----
__device__ __forceinline__ void cvt_chunk(const float* __restrict__ s,
                                          __hip_bfloat16* __restrict__ d)
{
  float4 v0 = *reinterpret_cast<const float4*>(s);
  float4 v1 = *reinterpret_cast<const float4*>(s + 4);
  *reinterpret_cast<uint4*>(d) = cvt8(v0, v1);
}

__global__ __launch_bounds__(256)
void convert_kernel(KParams p)
{
  const int id = blockIdx.x, t = threadIdx.x;
  if (id < 256)       { size_t c = (size_t)id*256 + t;        cvt_chunk(p.uk      + c*8, p.uk_bf  + c*8); }
  else if (id < 768)  { size_t c = (size_t)(id-256)*256 + t;  cvt_chunk(p.W_in    + c*8, p.Win_bf + c*8); }
  else if (id < 2816) { size_t c = (size_t)(id-768)*256 + t;  cvt_chunk(p.W_inproj+ c*8, p.Wip_bf + c*8); }
  else if (id < 3008) { size_t c = (size_t)(id-2816)*256 + t; cvt_chunk(p.W_x     + c*8, p.Wx_bf  + c*8); }
  else if (id < 4032) { size_t c = (size_t)(id-3008)*256 + t; cvt_chunk(p.W_out   + c*8, p.Wout_bf+ c*8); }
  else {               size_t c = (size_t)(id-4032)*256 + t;  // [W_dt|W_delta] -> 2048x128
    int row = (int)(c >> 4), col0 = ((int)c & 15)*8;
    const float* s = (col0 < 64) ? (p.W_dt    + (size_t)row*64 + col0)
                                 : (p.W_delta + (size_t)row*64 + (col0-64));
    cvt_chunk(s, p.Wdt128 + (size_t)row*128 + col0);
  }
}

// C[m,n] = sum_k A[m,k]*B[n,k], all-bf16 K-contiguous operands. 256 threads =
// 4 waves (2x2), wave tile 16x32, 16x16x32 bf16 MFMA, BK=64, LDS double-
// buffered; global loads issued after the barrier and consumed after the MFMA
// block so latency overlaps compute. R0-proven structure.
template<int BM, int BN, int WMT, int WNT, int EK>
__device__ __forceinline__ void gemm_tile(char* smemc, int bxi, int byi, int bzi,
    const __hip_bfloat16* __restrict__ Ap, const __hip_bfloat16* __restrict__ Bp,
    float* __restrict__ Coutp, int Ka, int Kb, int kLen, int N, const KParams& p)
{
  static_assert(BM == 32*WMT && BN == 32*WNT, "2x2 wave layout");
  constexpr int BK = 64, SA = 72;               // 144B rows keep 16B align
  constexpr int NA = (BM*BK)/(256*8);
  constexpr int NB = (BN*BK)/(256*8);
  ushort_t* sA = (ushort_t*)smemc;
  ushort_t* sB = (ushort_t*)(smemc + (size_t)2*BM*SA*sizeof(ushort_t));
  const int tid  = threadIdx.x;
  const int wave = tid >> 6, lane = tid & 63;
  const int wm = wave >> 1, wn = wave & 1;
  const int r = lane & 15, q = lane >> 4;
  const int bm = byi * BM, bn = bxi * BN;
  const int kBase = bzi * kLen;
  const int T = kLen / BK;

  uint4 ua[NA], ub[NB];

  auto loadTiles = [&](int k0) {
    #pragma unroll
    for (int c=0;c<NA;++c) {
      int idx = tid*8 + c*2048; int row = idx>>6, kk = idx&63;
      ua[c] = *reinterpret_cast<const uint4*>(Ap + (size_t)(bm+row)*Ka + k0 + kk);
    }
    #pragma unroll
    for (int c=0;c<NB;++c) {
      int idx = tid*8 + c*2048; int row = idx>>6, kk = idx&63;
      ub[c] = *reinterpret_cast<const uint4*>(Bp + (size_t)(bn+row)*Kb + k0 + kk);
    }
  };
  auto writeTiles = [&](int buf) {
    #pragma unroll
    for (int c=0;c<NA;++c) {
      int idx = tid*8 + c*2048; int row = idx>>6, kk = idx&63;
      *reinterpret_cast<uint4*>(&sA[buf*(BM*SA) + row*SA + kk]) = ua[c];
    }
    #pragma unroll
    for (int c=0;c<NB;++c) {
      int idx = tid*8 + c*2048; int row = idx>>6, kk = idx&63;
      *reinterpret_cast<uint4*>(&sB[buf*(BN*SA) + row*SA + kk]) = ub[c];
    }
  };

  f32x4 acc[WMT][WNT];
  #pragma unroll
  for (int i=0;i<WMT;++i)
    #pragma unroll
    for (int j=0;j<WNT;++j) acc[i][j] = (f32x4){0.f,0.f,0.f,0.f};

  loadTiles(kBase);
  writeTiles(0);
  for (int t=0; t<T; ++t) {
    __syncthreads();
    const int cur = t & 1;
    if (t+1 < T) loadTiles(kBase + (t+1)*BK);   // overlaps MFMA below
    #pragma unroll
    for (int ks=0; ks<2; ++ks) {
      bf16x8 af[WMT], bfr[WNT];
      #pragma unroll
      for (int mt=0; mt<WMT; ++mt)
        af[mt] = *reinterpret_cast<const bf16x8*>(&sA[cur*(BM*SA) + (wm*(WMT*16)+mt*16+r)*SA + ks*32 + q*8]);
      #pragma unroll
      for (int nt=0; nt<WNT; ++nt)
        bfr[nt] = *reinterpret_cast<const bf16x8*>(&sB[cur*(BN*SA) + (wn*(WNT*16)+nt*16+r)*SA + ks*32 + q*8]);
      #pragma unroll
      for (int mt=0; mt<WMT; ++mt)
        #pragma unroll
        for (int nt=0; nt<WNT; ++nt)
          acc[mt][nt] = __builtin_amdgcn_mfma_f32_16x16x32_bf16(af[mt], bfr[nt], acc[mt][nt], 0,0,0);
    }
    if (t+1 < T) writeTiles(cur ^ 1);
  }

  #pragma unroll
  for (int mt=0; mt<WMT; ++mt) {
    #pragma unroll
    for (int nt=0; nt<WNT; ++nt) {
      #pragma unroll
      for (int i=0;i<4;++i) {
        int grow = bm + wm*(WMT*16) + mt*16 + q*4 + i;
        int gcol = bn + wn*(WNT*16) + nt*16 + r;
        float v = acc[mt][nt][i];
        if constexpr (EK == EPI_PART) {
          float* P = Coutp + (size_t)bzi * ((size_t)B_*N);
          P[(size_t)grow*N + gcol] = v;
        } else if constexpr (EK == EPI_G2) {
          if (gcol < DI) {  // x half: conv last tap + silu
            float xc = v * p.conv_w[gcol*DC + (DC-1)] + p.conv_b[gcol];
            p.Xs[(size_t)grow*DI + gcol] = f2bf(siluf_(xc));
          } else {          // z half: silu(z)
            p.Sz[(size_t)grow*DI + (gcol - DI)] = f2bf(siluf_(v));
          }
        } else {            // EPI_G4
          float dt  = softplusf_(v + p.dt_bias[gcol]);
          float xsv = bf2f(p.Xs[(size_t)grow*DI + gcol]);
          float szv = bf2f(p.Sz[(size_t)grow*DI + gcol]);
          float y = (dt * xsv * p.bc[grow] + p.D_skip[gcol] * xsv) * szv;
          p.Yb[(size_t)grow*DI + gcol] = f2bf(y);
        }
      }
    }
  }
}

// ---- routing / kan ----

__device__ __forceinline__ void route(float t, const float* rW, const float* rb,
                                      float* w, float* mask, float* wn)
{
  float l[E_];
  float m = -1e30f;
  for (int e=0;e<E_;++e){ l[e] = t*rW[e] + rb[e]; m = fmaxf(m, l[e]); }
  float s = 0.f;
  for (int e=0;e<E_;++e){ w[e] = expf(l[e]-m); s += w[e]; }
  for (int e=0;e<E_;++e) w[e] /= s;
  int i1 = 0;
  for (int e=1;e<E_;++e) if (w[e] > w[i1]) i1 = e;
  int i2 = -1;
  for (int e=0;e<E_;++e) if (e != i1 && (i2 < 0 || w[e] > w[i2])) i2 = e;
  float ssel = w[i1] + w[i2] + 1e-8f;
  for (int e=0;e<E_;++e){
    float mk = (e==i1 || e==i2) ? 1.f : 0.f;
    mask[e] = mk;
    wn[e] = mk * w[e] / ssel;
  }
}

// One job = 4 batch rows, one per wave. dphi slices live in the shared scratch.
__device__ __forceinline__ void kan_job(char* smemc, int job, const KParams& p)
{
  float* dphi = (float*)smemc;                  // 4 waves x 512 floats = 8 KB
  const int wv = threadIdx.x >> 6, lane = threadIdx.x & 63;
  const int b = job*4 + wv;
  {
    float t  = p.tk_c[b];
    float tp = p.tk_p[b];
    float w_c[E_], mk_c[E_], wn_c[E_];
    float w_p[E_], mk_p[E_], wn_p[E_];
    route(t,  p.rW, p.rb, w_c, mk_c, wn_c);
    route(tp, p.rW, p.rb, w_p, mk_p, wn_p);
    if (lane < E_) {
      p.out_w[b*E_ + lane]    = w_c[lane];
      p.out_mask[b*E_ + lane] = mk_c[lane];
    }
    float ec = 0.f, epv = 0.f;
    #pragma unroll
    for (int e=0;e<E_;++e) {
      float f  = p.freq[e*DT + lane];
      float ph = p.phase[e*DT + lane];
      ec  += wn_c[e] * sinf(t*f + ph);
      epv += wn_p[e] * sinf(tp*f + ph);
    }
    const float h = 2.f/(G_-1);
    #pragma unroll
    for (int g=0; g<G_; ++g) {
      float gr = -1.f + g*h;
      float a  = (ec - gr)/h;
      float bb = (epv - gr)/h;
      dphi[wv*512 + lane*G_ + g] = expf(-a*a) - expf(-bb*bb);
    }
  }
  __syncthreads();
  {
    float accv = 0.f;
    const float* kw = p.kanW + (size_t)lane*(DT*G_);
    const float* dd = dphi + wv*512;
    #pragma unroll 4
    for (int j=0;j<DT*G_;j+=4) {
      float4 kv = *reinterpret_cast<const float4*>(kw + j);
      float4 dv = *reinterpret_cast<const float4*>(dd + j);   // LDS broadcast
      accv += kv.x*dv.x + kv.y*dv.y + kv.z*dv.z + kv.w*dv.w;
    }
    p.Acat[b*128 + 64 + lane] = f2bf(accv);
  }
}

// ---- kernels ----

// K1: G1 split-K x4 (1024 tiles, R0 grid/order) + mote/kan (128 jobs).
__global__ __launch_bounds__(256)
void g1kan_kernel(KParams p)
{
  __shared__ __align__(16) char smem[(2*32*72 + 2*64*72)*2];   // 27648 B
  const int id = blockIdx.x;
  if (id < 1024) {
    const int bxi = id & 15, byi = (id >> 4) & 15, bzi = id >> 8;  // x-fastest (R0)
    gemm_tile<32,64,1,2,EPI_PART>(smem, bxi, byi, bzi,
        p.uk_bf, p.Win_bf, p.Part, DM, DM, 256, DM, p);
  } else {
    kan_job(smem, id - 1024, p);
  }
}

// Generic GEMM, x-fastest flattened wg order (identical to R0's dim3 order).
template<int BM, int BN, int WMT, int WNT, int NT, int MT, int EK>
__global__ __launch_bounds__(256)
void gemm_xfirst(const __hip_bfloat16* __restrict__ Ap, const __hip_bfloat16* __restrict__ Bp,
                 float* __restrict__ Coutp, int Ka, int Kb, int kLen, int N, KParams p)
{
  __shared__ __align__(16) char smem[(2*BM*72 + 2*BN*72)*2];
  const int id = blockIdx.x;
  const int bxi = id % NT;
  const int rem = id / NT;
  const int byi = rem % MT;
  const int bzi = rem / MT;
  gemm_tile<BM,BN,WMT,WNT,EK>(smem, bxi, byi, bzi, Ap, Bp, Coutp, Ka, Kb, kLen, N, p);
}

// Pu = f2bf(sum_{s<4} part[s] + bias)
__global__ __launch_bounds__(256)
void reduce_bias_kernel(KParams p)
{
  const int i = blockIdx.x*256 + threadIdx.x;       // float4 index
  const int total = B_*DM/4;
  const float4* pp = (const float4*)p.Part;
  float4 s = pp[i];
  #pragma unroll
  for (int k=1;k<4;++k){ float4 t = pp[i + k*total]; s.x+=t.x; s.y+=t.y; s.z+=t.z; s.w+=t.w; }
  float4 bv = ((const float4*)p.b_in)[i & (DM/4 - 1)];
  uint2 o; o.x = pack2(s.x+bv.x, s.y+bv.y); o.y = pack2(s.z+bv.z, s.w+bv.w);
  ((uint2*)p.Pu)[i] = o;
}

// x_dbl reduce (8 splits): col<64 -> Acat[:,0:64] bf16 (dt_r); cols 64..191
// are B,C — stash in LDS, bc[row] = dot(B,C) via wave reduce. One row per wg.
__global__ __launch_bounds__(192)
void reduce_g3_kernel(KParams p)
{
  const int row = blockIdx.x, col = threadIdx.x;    // 192 threads
  const int stride = B_*192;
  float s = 0.f;
  #pragma unroll
  for (int k=0;k<8;++k) s += p.Part[(size_t)k*stride + row*192 + col];
  __shared__ float sBC[128];
  if (col < 64) p.Acat[row*128 + col] = f2bf(s);
  else          sBC[col-64] = s;
  __syncthreads();
  if (col < 64) {
    float pval = sBC[col] * sBC[col+64];
    #pragma unroll
    for (int off=32; off; off>>=1) pval += __shfl_down(pval, off);
    if (col == 0) p.bc[row] = pval;
  }
}

// hk = sum_{s<4} part[s]  (f32 out)
__global__ __launch_bounds__(256)
void reduce_plain_kernel(KParams p)
{
  const int i = blockIdx.x*256 + threadIdx.x;
  const int total = B_*DM/4;
  const float4* pp = (const float4*)p.Part;
  float4 s = pp[i];
  #pragma unroll
  for (int k=1;k<4;++k){ float4 t = pp[i + k*total]; s.x+=t.x; s.y+=t.y; s.z+=t.z; s.w+=t.w; }
  ((float4*)p.out_hk)[i] = s;
}

extern "C" void kernel_launch(void* const* d_in, const int* in_sizes, int n_in,
                              void* d_out, int out_size, void* d_ws, size_t ws_size,
                              hipStream_t stream)
{
  KParams p;
  p.uk       = (const float*)d_in[0];
  p.tk_c     = (const float*)d_in[1];
  p.tk_p     = (const float*)d_in[2];
  p.W_in     = (const float*)d_in[3];
  p.b_in     = (const float*)d_in[4];
  p.rW       = (const float*)d_in[5];
  p.rb       = (const float*)d_in[6];
  p.freq     = (const float*)d_in[7];
  p.phase    = (const float*)d_in[8];
  p.kanW     = (const float*)d_in[9];
  p.W_inproj = (const float*)d_in[10];
  p.conv_w   = (const float*)d_in[11];
  p.conv_b   = (const float*)d_in[12];
  p.W_x      = (const float*)d_in[13];
  p.W_dt     = (const float*)d_in[14];
  p.dt_bias  = (const float*)d_in[15];
  p.W_delta  = (const float*)d_in[16];
  p.D_skip   = (const float*)d_in[18];
  p.W_out    = (const float*)d_in[19];

  char* ws = (char*)d_ws;
  p.Pu     = (__hip_bfloat16*)(ws);                                // 1 MB
  p.Xs     = (__hip_bfloat16*)(ws + (size_t)(1<<20));              // 2 MB
  p.Sz     = (__hip_bfloat16*)(ws + (size_t)3*(1<<20));            // 2 MB
  p.Yb     = (__hip_bfloat16*)(ws + (size_t)5*(1<<20));            // 2 MB
  p.Acat   = (__hip_bfloat16*)(ws + (size_t)7*(1<<20));            // 128 KB
  p.bc     = (float*)         (ws + (size_t)7*(1<<20) + (128<<10));// 2 KB
  p.Part   = (float*)         (ws + (size_t)8*(1<<20));            // 8 MB
  p.uk_bf  = (__hip_bfloat16*)(ws + (size_t)16*(1<<20));           // 1 MB
  p.Win_bf = (__hip_bfloat16*)(ws + (size_t)17*(1<<20));           // 2 MB
  p.Wip_bf = (__hip_bfloat16*)(ws + (size_t)19*(1<<20));           // 8 MB
  p.Wx_bf  = (__hip_bfloat16*)(ws + (size_t)27*(1<<20));           // 768 KB
  p.Wdt128 = (__hip_bfloat16*)(ws + (size_t)28*(1<<20));           // 512 KB
  p.Wout_bf= (__hip_bfloat16*)(ws + (size_t)29*(1<<20));           // 4 MB

  p.out_hk   = (float*)d_out;
  p.out_w    = p.out_hk + (size_t)B_*DM;
  p.out_mask = p.out_w  + (size_t)B_*E_;

  // K0: f32 -> bf16 pre-convert of uk + all GEMM B operands (one pass)
  convert_kernel<<<dim3(4160), 256, 0, stream>>>(p);

  // K1: G1 (pu partials, split-K x4, 1024 wgs) + mote/kan (128 wgs)
  g1kan_kernel<<<dim3(1152), 256, 0, stream>>>(p);
  reduce_bias_kernel<<<dim3(512), 256, 0, stream>>>(p);

  // G2: xz = pu @ W_inproj^T (512x4096x1024), conv+silu / silu fused. 1024 wgs.
  gemm_xfirst<32,64,1,2,64,16,EPI_G2><<<dim3(1024), 256, 0, stream>>>(
      p.Pu, p.Wip_bf, nullptr, DM, DM, DM, 2*DI, p);

  // G3: x_dbl = xs @ W_x^T (512x192x2048), split-K x8 -> partials. 384 wgs.
  gemm_xfirst<32,64,1,2,3,16,EPI_PART><<<dim3(384), 256, 0, stream>>>(
      p.Xs, p.Wx_bf, p.Part, DI, DI, 256, 192, p);
  reduce_g3_kernel<<<dim3(512), 192, 0, stream>>>(p);

  // G4: dt GEMM (512x2048x128, B=Wdt128) + softplus + y fusion. 512 wgs.
  gemm_xfirst<32,64,1,2,32,16,EPI_G4><<<dim3(512), 256, 0, stream>>>(
      p.Acat, p.Wdt128, nullptr, 128, 128, 128, DI, p);

  // G5: hk = y @ W_out^T (512x1024x2048), split-K x4 -> partials. 1024 wgs.
  gemm_xfirst<32,64,1,2,16,16,EPI_PART><<<dim3(1024), 256, 0, stream>>>(
      p.Yb, p.Wout_bf, p.Part, DI, DI, 512, DM, p);
  reduce_plain_kernel<<<dim3(512), 256, 0, stream>>>(p);
}

// Round 6
// 184.970 us; speedup vs baseline: 1.2168x; 1.2168x over previous
//
#include <hip/hip_runtime.h>
#include <hip/hip_bf16.h>
#include <math.h>

#define B_  512
#define DM  1024
#define DI  2048
#define DS  64
#define DTR 64
#define DT  64
#define G_  8
#define E_  4
#define DC  4

typedef __bf16 bf16x8 __attribute__((ext_vector_type(8)));
typedef float  f32x4  __attribute__((ext_vector_type(4)));
typedef unsigned short ushort_t;

__device__ __forceinline__ float bf2f(__hip_bfloat16 h) { return __bfloat162float(h); }
__device__ __forceinline__ __hip_bfloat16 f2bf(float f) { return __float2bfloat16(f); }
__device__ __forceinline__ float sigmoidf_(float x){ return 1.f/(1.f+expf(-x)); }
__device__ __forceinline__ float siluf_(float x){ return x*sigmoidf_(x); }
__device__ __forceinline__ float softplusf_(float x){ return (x>20.f)? x : log1pf(expf(x)); }

__device__ __forceinline__ unsigned int pack2(float a, float b) {
  unsigned short ua = __builtin_bit_cast(unsigned short, (__bf16)a);
  unsigned short ub = __builtin_bit_cast(unsigned short, (__bf16)b);
  return (unsigned int)ua | ((unsigned int)ub << 16);
}
__device__ __forceinline__ uint4 cvt8(float4 v0, float4 v1) {
  uint4 r;
  r.x = pack2(v0.x, v0.y); r.y = pack2(v0.z, v0.w);
  r.z = pack2(v1.x, v1.y); r.w = pack2(v1.z, v1.w);
  return r;
}

enum EpiKind { EPI_PART=0, EPI_G2=1, EPI_G4=2 };

struct KParams {
  const float *uk, *tk_c, *tk_p, *W_in, *b_in, *rW, *rb, *freq, *phase, *kanW;
  const float *W_inproj, *conv_w, *conv_b, *W_x, *W_dt, *dt_bias, *W_delta, *D_skip, *W_out;
  __hip_bfloat16 *Pu, *Xs, *Sz, *Yb, *Acat;
  __hip_bfloat16 *uk_bf, *Win_bf, *Wip_bf, *Wx_bf, *Wdt128, *Wout_bf;
  float *bc, *Part, *out_hk, *out_w, *out_mask;
};

// ---- weight/activation f32 -> bf16 pre-convert (one streaming pass) ----
__device__ __forceinline__ void cvt_chunk(const float* __restrict__ s,
                                          __hip_bfloat16* __restrict__ d)
{
  float4 v0 = *reinterpret_cast<const float4*>(s);
  float4 v1 = *reinterpret_cast<const float4*>(s + 4);
  *reinterpret_cast<uint4*>(d) = cvt8(v0, v1);
}

__global__ __launch_bounds__(256)
void convert_kernel(KParams p)
{
  const int id = blockIdx.x, t = threadIdx.x;
  if (id < 256)       { size_t c = (size_t)id*256 + t;        cvt_chunk(p.uk      + c*8, p.uk_bf  + c*8); }
  else if (id < 768)  { size_t c = (size_t)(id-256)*256 + t;  cvt_chunk(p.W_in    + c*8, p.Win_bf + c*8); }
  else if (id < 2816) { size_t c = (size_t)(id-768)*256 + t;  cvt_chunk(p.W_inproj+ c*8, p.Wip_bf + c*8); }
  else if (id < 3008) { size_t c = (size_t)(id-2816)*256 + t; cvt_chunk(p.W_x     + c*8, p.Wx_bf  + c*8); }
  else if (id < 4032) { size_t c = (size_t)(id-3008)*256 + t; cvt_chunk(p.W_out   + c*8, p.Wout_bf+ c*8); }
  else {               size_t c = (size_t)(id-4032)*256 + t;  // [W_dt|W_delta] -> 2048x128
    int row = (int)(c >> 4), col0 = ((int)c & 15)*8;
    const float* s = (col0 < 64) ? (p.W_dt    + (size_t)row*64 + col0)
                                 : (p.W_delta + (size_t)row*64 + (col0-64));
    cvt_chunk(s, p.Wdt128 + (size_t)row*128 + col0);
  }
}

// C[m,n] = sum_k A[m,k]*B[n,k], all-bf16 K-contiguous operands. 256 threads =
// 4 waves (2x2), wave tile 16x32, 16x16x32 bf16 MFMA. BK=128: 96 B/thread of
// global loads per barrier interval (the compiler's vmcnt(0)-before-s_barrier
// caps in-flight bytes at one K-step's issues — BK=64 gave only 48 B and
// ~726 GB/s staging; see R5 counters). LDS double-buffered, 52 KB.
template<int BM, int BN, int WMT, int WNT, int EK>
__device__ __forceinline__ void gemm_tile(char* smemc, int bxi, int byi, int bzi,
    const __hip_bfloat16* __restrict__ Ap, const __hip_bfloat16* __restrict__ Bp,
    float* __restrict__ Coutp, int Ka, int Kb, int kLen, int N, const KParams& p)
{
  static_assert(BM == 32*WMT && BN == 32*WNT, "2x2 wave layout");
  constexpr int BK = 128, SA = 136;             // 272B rows keep 16B align
  constexpr int NA = (BM*BK)/(256*8);
  constexpr int NB = (BN*BK)/(256*8);
  ushort_t* sA = (ushort_t*)smemc;
  ushort_t* sB = (ushort_t*)(smemc + (size_t)2*BM*SA*sizeof(ushort_t));
  const int tid  = threadIdx.x;
  const int wave = tid >> 6, lane = tid & 63;
  const int wm = wave >> 1, wn = wave & 1;
  const int r = lane & 15, q = lane >> 4;
  const int bm = byi * BM, bn = bxi * BN;
  const int kBase = bzi * kLen;
  const int T = kLen / BK;

  uint4 ua[NA], ub[NB];

  auto loadTiles = [&](int k0) {
    #pragma unroll
    for (int c=0;c<NA;++c) {
      int idx = tid*8 + c*2048; int row = idx>>7, kk = idx&127;
      ua[c] = *reinterpret_cast<const uint4*>(Ap + (size_t)(bm+row)*Ka + k0 + kk);
    }
    #pragma unroll
    for (int c=0;c<NB;++c) {
      int idx = tid*8 + c*2048; int row = idx>>7, kk = idx&127;
      ub[c] = *reinterpret_cast<const uint4*>(Bp + (size_t)(bn+row)*Kb + k0 + kk);
    }
  };
  auto writeTiles = [&](int buf) {
    #pragma unroll
    for (int c=0;c<NA;++c) {
      int idx = tid*8 + c*2048; int row = idx>>7, kk = idx&127;
      *reinterpret_cast<uint4*>(&sA[buf*(BM*SA) + row*SA + kk]) = ua[c];
    }
    #pragma unroll
    for (int c=0;c<NB;++c) {
      int idx = tid*8 + c*2048; int row = idx>>7, kk = idx&127;
      *reinterpret_cast<uint4*>(&sB[buf*(BN*SA) + row*SA + kk]) = ub[c];
    }
  };

  f32x4 acc[WMT][WNT];
  #pragma unroll
  for (int i=0;i<WMT;++i)
    #pragma unroll
    for (int j=0;j<WNT;++j) acc[i][j] = (f32x4){0.f,0.f,0.f,0.f};

  loadTiles(kBase);
  writeTiles(0);
  for (int t=0; t<T; ++t) {
    __syncthreads();
    const int cur = t & 1;
    if (t+1 < T) loadTiles(kBase + (t+1)*BK);   // overlaps MFMA below
    #pragma unroll
    for (int ks=0; ks<4; ++ks) {
      bf16x8 af[WMT], bfr[WNT];
      #pragma unroll
      for (int mt=0; mt<WMT; ++mt)
        af[mt] = *reinterpret_cast<const bf16x8*>(&sA[cur*(BM*SA) + (wm*(WMT*16)+mt*16+r)*SA + ks*32 + q*8]);
      #pragma unroll
      for (int nt=0; nt<WNT; ++nt)
        bfr[nt] = *reinterpret_cast<const bf16x8*>(&sB[cur*(BN*SA) + (wn*(WNT*16)+nt*16+r)*SA + ks*32 + q*8]);
      #pragma unroll
      for (int mt=0; mt<WMT; ++mt)
        #pragma unroll
        for (int nt=0; nt<WNT; ++nt)
          acc[mt][nt] = __builtin_amdgcn_mfma_f32_16x16x32_bf16(af[mt], bfr[nt], acc[mt][nt], 0,0,0);
    }
    if (t+1 < T) writeTiles(cur ^ 1);
  }

  #pragma unroll
  for (int mt=0; mt<WMT; ++mt) {
    #pragma unroll
    for (int nt=0; nt<WNT; ++nt) {
      #pragma unroll
      for (int i=0;i<4;++i) {
        int grow = bm + wm*(WMT*16) + mt*16 + q*4 + i;
        int gcol = bn + wn*(WNT*16) + nt*16 + r;
        float v = acc[mt][nt][i];
        if constexpr (EK == EPI_PART) {
          float* P = Coutp + (size_t)bzi * ((size_t)B_*N);
          P[(size_t)grow*N + gcol] = v;
        } else if constexpr (EK == EPI_G2) {
          if (gcol < DI) {  // x half: conv last tap + silu
            float xc = v * p.conv_w[gcol*DC + (DC-1)] + p.conv_b[gcol];
            p.Xs[(size_t)grow*DI + gcol] = f2bf(siluf_(xc));
          } else {          // z half: silu(z)
            p.Sz[(size_t)grow*DI + (gcol - DI)] = f2bf(siluf_(v));
          }
        } else {            // EPI_G4
          float dt  = softplusf_(v + p.dt_bias[gcol]);
          float xsv = bf2f(p.Xs[(size_t)grow*DI + gcol]);
          float szv = bf2f(p.Sz[(size_t)grow*DI + gcol]);
          float y = (dt * xsv * p.bc[grow] + p.D_skip[gcol] * xsv) * szv;
          p.Yb[(size_t)grow*DI + gcol] = f2bf(y);
        }
      }
    }
  }
}

// ---- routing / kan ----

__device__ __forceinline__ void route(float t, const float* rW, const float* rb,
                                      float* w, float* mask, float* wn)
{
  float l[E_];
  float m = -1e30f;
  for (int e=0;e<E_;++e){ l[e] = t*rW[e] + rb[e]; m = fmaxf(m, l[e]); }
  float s = 0.f;
  for (int e=0;e<E_;++e){ w[e] = expf(l[e]-m); s += w[e]; }
  for (int e=0;e<E_;++e) w[e] /= s;
  int i1 = 0;
  for (int e=1;e<E_;++e) if (w[e] > w[i1]) i1 = e;
  int i2 = -1;
  for (int e=0;e<E_;++e) if (e != i1 && (i2 < 0 || w[e] > w[i2])) i2 = e;
  float ssel = w[i1] + w[i2] + 1e-8f;
  for (int e=0;e<E_;++e){
    float mk = (e==i1 || e==i2) ? 1.f : 0.f;
    mask[e] = mk;
    wn[e] = mk * w[e] / ssel;
  }
}

// One job = 4 batch rows, one per wave. dphi slices live in the shared scratch.
__device__ __forceinline__ void kan_job(char* smemc, int job, const KParams& p)
{
  float* dphi = (float*)smemc;                  // 4 waves x 512 floats = 8 KB
  const int wv = threadIdx.x >> 6, lane = threadIdx.x & 63;
  const int b = job*4 + wv;
  {
    float t  = p.tk_c[b];
    float tp = p.tk_p[b];
    float w_c[E_], mk_c[E_], wn_c[E_];
    float w_p[E_], mk_p[E_], wn_p[E_];
    route(t,  p.rW, p.rb, w_c, mk_c, wn_c);
    route(tp, p.rW, p.rb, w_p, mk_p, wn_p);
    if (lane < E_) {
      p.out_w[b*E_ + lane]    = w_c[lane];
      p.out_mask[b*E_ + lane] = mk_c[lane];
    }
    float ec = 0.f, epv = 0.f;
    #pragma unroll
    for (int e=0;e<E_;++e) {
      float f  = p.freq[e*DT + lane];
      float ph = p.phase[e*DT + lane];
      ec  += wn_c[e] * sinf(t*f + ph);
      epv += wn_p[e] * sinf(tp*f + ph);
    }
    const float h = 2.f/(G_-1);
    #pragma unroll
    for (int g=0; g<G_; ++g) {
      float gr = -1.f + g*h;
      float a  = (ec - gr)/h;
      float bb = (epv - gr)/h;
      dphi[wv*512 + lane*G_ + g] = expf(-a*a) - expf(-bb*bb);
    }
  }
  __syncthreads();
  {
    float accv = 0.f;
    const float* kw = p.kanW + (size_t)lane*(DT*G_);
    const float* dd = dphi + wv*512;
    #pragma unroll 4
    for (int j=0;j<DT*G_;j+=4) {
      float4 kv = *reinterpret_cast<const float4*>(kw + j);
      float4 dv = *reinterpret_cast<const float4*>(dd + j);   // LDS broadcast
      accv += kv.x*dv.x + kv.y*dv.y + kv.z*dv.z + kv.w*dv.w;
    }
    p.Acat[b*128 + 64 + lane] = f2bf(accv);
  }
}

// ---- kernels (one symbol per stage so rocprof top-5 identifies the stage) ----

#define GEMM_SMEM(BM,BN) ((2*(BM)*136 + 2*(BN)*136)*2)

// K1: G1 split-K x4 (1024 tiles, x-fastest) + mote/kan (128 jobs).
__global__ __launch_bounds__(256)
void g1kan_kernel(KParams p)
{
  __shared__ __align__(16) char smem[GEMM_SMEM(32,64)];   // 52224 B
  const int id = blockIdx.x;
  if (id < 1024) {
    const int bxi = id & 15, byi = (id >> 4) & 15, bzi = id >> 8;
    gemm_tile<32,64,1,2,EPI_PART>(smem, bxi, byi, bzi,
        p.uk_bf, p.Win_bf, p.Part, DM, DM, 256, DM, p);
  } else {
    kan_job(smem, id - 1024, p);
  }
}

// G2: xz = pu @ W_inproj^T (512x4096x1024), conv+silu / silu fused. 1024 wgs.
__global__ __launch_bounds__(256)
void g2_kernel(KParams p)
{
  __shared__ __align__(16) char smem[GEMM_SMEM(32,64)];
  const int bxi = blockIdx.x & 63, byi = blockIdx.x >> 6;
  gemm_tile<32,64,1,2,EPI_G2>(smem, bxi, byi, 0, p.Pu, p.Wip_bf, nullptr, DM, DM, DM, 2*DI, p);
}

// G3: x_dbl = xs @ W_x^T (512x192x2048), split-K x8 -> partials. 384 wgs.
__global__ __launch_bounds__(256)
void g3_kernel(KParams p)
{
  __shared__ __align__(16) char smem[GEMM_SMEM(32,64)];
  const int bxi = blockIdx.x % 3, rem = blockIdx.x / 3;
  const int byi = rem & 15, bzi = rem >> 4;
  gemm_tile<32,64,1,2,EPI_PART>(smem, bxi, byi, bzi, p.Xs, p.Wx_bf, p.Part, DI, DI, 256, 192, p);
}

// G4: dt GEMM (512x2048x128, B=Wdt128) + softplus + y fusion. 512 wgs.
__global__ __launch_bounds__(256)
void g4_kernel(KParams p)
{
  __shared__ __align__(16) char smem[GEMM_SMEM(32,64)];
  const int bxi = blockIdx.x & 31, byi = blockIdx.x >> 5;
  gemm_tile<32,64,1,2,EPI_G4>(smem, bxi, byi, 0, p.Acat, p.Wdt128, nullptr, 128, 128, 128, DI, p);
}

// G5: hk = y @ W_out^T (512x1024x2048), split-K x4 -> partials. 1024 wgs.
__global__ __launch_bounds__(256)
void g5_kernel(KParams p)
{
  __shared__ __align__(16) char smem[GEMM_SMEM(32,64)];
  const int bxi = blockIdx.x & 15, rem = blockIdx.x >> 4;
  const int byi = rem & 15, bzi = rem >> 4;
  gemm_tile<32,64,1,2,EPI_PART>(smem, bxi, byi, bzi, p.Yb, p.Wout_bf, p.Part, DI, DI, 512, DM, p);
}

// Pu = f2bf(sum_{s<4} part[s] + bias)
__global__ __launch_bounds__(256)
void reduce_bias_kernel(KParams p)
{
  const int i = blockIdx.x*256 + threadIdx.x;       // float4 index
  const int total = B_*DM/4;
  const float4* pp = (const float4*)p.Part;
  float4 s = pp[i];
  #pragma unroll
  for (int k=1;k<4;++k){ float4 t = pp[i + k*total]; s.x+=t.x; s.y+=t.y; s.z+=t.z; s.w+=t.w; }
  float4 bv = ((const float4*)p.b_in)[i & (DM/4 - 1)];
  uint2 o; o.x = pack2(s.x+bv.x, s.y+bv.y); o.y = pack2(s.z+bv.z, s.w+bv.w);
  ((uint2*)p.Pu)[i] = o;
}

// x_dbl reduce (8 splits): col<64 -> Acat[:,0:64] bf16 (dt_r); cols 64..191
// are B,C — stash in LDS, bc[row] = dot(B,C) via wave reduce. One row per wg.
__global__ __launch_bounds__(192)
void reduce_g3_kernel(KParams p)
{
  const int row = blockIdx.x, col = threadIdx.x;    // 192 threads
  const int stride = B_*192;
  float s = 0.f;
  #pragma unroll
  for (int k=0;k<8;++k) s += p.Part[(size_t)k*stride + row*192 + col];
  __shared__ float sBC[128];
  if (col < 64) p.Acat[row*128 + col] = f2bf(s);
  else          sBC[col-64] = s;
  __syncthreads();
  if (col < 64) {
    float pval = sBC[col] * sBC[col+64];
    #pragma unroll
    for (int off=32; off; off>>=1) pval += __shfl_down(pval, off);
    if (col == 0) p.bc[row] = pval;
  }
}

// hk = sum_{s<4} part[s]  (f32 out)
__global__ __launch_bounds__(256)
void reduce_plain_kernel(KParams p)
{
  const int i = blockIdx.x*256 + threadIdx.x;
  const int total = B_*DM/4;
  const float4* pp = (const float4*)p.Part;
  float4 s = pp[i];
  #pragma unroll
  for (int k=1;k<4;++k){ float4 t = pp[i + k*total]; s.x+=t.x; s.y+=t.y; s.z+=t.z; s.w+=t.w; }
  ((float4*)p.out_hk)[i] = s;
}

extern "C" void kernel_launch(void* const* d_in, const int* in_sizes, int n_in,
                              void* d_out, int out_size, void* d_ws, size_t ws_size,
                              hipStream_t stream)
{
  KParams p;
  p.uk       = (const float*)d_in[0];
  p.tk_c     = (const float*)d_in[1];
  p.tk_p     = (const float*)d_in[2];
  p.W_in     = (const float*)d_in[3];
  p.b_in     = (const float*)d_in[4];
  p.rW       = (const float*)d_in[5];
  p.rb       = (const float*)d_in[6];
  p.freq     = (const float*)d_in[7];
  p.phase    = (const float*)d_in[8];
  p.kanW     = (const float*)d_in[9];
  p.W_inproj = (const float*)d_in[10];
  p.conv_w   = (const float*)d_in[11];
  p.conv_b   = (const float*)d_in[12];
  p.W_x      = (const float*)d_in[13];
  p.W_dt     = (const float*)d_in[14];
  p.dt_bias  = (const float*)d_in[15];
  p.W_delta  = (const float*)d_in[16];
  p.D_skip   = (const float*)d_in[18];
  p.W_out    = (const float*)d_in[19];

  char* ws = (char*)d_ws;
  p.Pu     = (__hip_bfloat16*)(ws);                                // 1 MB
  p.Xs     = (__hip_bfloat16*)(ws + (size_t)(1<<20));              // 2 MB
  p.Sz     = (__hip_bfloat16*)(ws + (size_t)3*(1<<20));            // 2 MB
  p.Yb     = (__hip_bfloat16*)(ws + (size_t)5*(1<<20));            // 2 MB
  p.Acat   = (__hip_bfloat16*)(ws + (size_t)7*(1<<20));            // 128 KB
  p.bc     = (float*)         (ws + (size_t)7*(1<<20) + (128<<10));// 2 KB
  p.Part   = (float*)         (ws + (size_t)8*(1<<20));            // 8 MB
  p.uk_bf  = (__hip_bfloat16*)(ws + (size_t)16*(1<<20));           // 1 MB
  p.Win_bf = (__hip_bfloat16*)(ws + (size_t)17*(1<<20));           // 2 MB
  p.Wip_bf = (__hip_bfloat16*)(ws + (size_t)19*(1<<20));           // 8 MB
  p.Wx_bf  = (__hip_bfloat16*)(ws + (size_t)27*(1<<20));           // 768 KB
  p.Wdt128 = (__hip_bfloat16*)(ws + (size_t)28*(1<<20));           // 512 KB
  p.Wout_bf= (__hip_bfloat16*)(ws + (size_t)29*(1<<20));           // 4 MB

  p.out_hk   = (float*)d_out;
  p.out_w    = p.out_hk + (size_t)B_*DM;
  p.out_mask = p.out_w  + (size_t)B_*E_;

  // K0: f32 -> bf16 pre-convert of uk + all GEMM B operands (one pass)
  convert_kernel<<<dim3(4160), 256, 0, stream>>>(p);

  // K1: G1 (pu partials, split-K x4, 1024 wgs) + mote/kan (128 wgs)
  g1kan_kernel<<<dim3(1152), 256, 0, stream>>>(p);
  reduce_bias_kernel<<<dim3(512), 256, 0, stream>>>(p);

  // G2
  g2_kernel<<<dim3(1024), 256, 0, stream>>>(p);

  // G3 + reduce
  g3_kernel<<<dim3(384), 256, 0, stream>>>(p);
  reduce_g3_kernel<<<dim3(512), 192, 0, stream>>>(p);

  // G4
  g4_kernel<<<dim3(512), 256, 0, stream>>>(p);

  // G5 + reduce
  g5_kernel<<<dim3(1024), 256, 0, stream>>>(p);
  reduce_plain_kernel<<<dim3(512), 256, 0, stream>>>(p);
}

// Round 7
// 175.922 us; speedup vs baseline: 1.2794x; 1.0514x over previous
//
#include <hip/hip_runtime.h>
#include <hip/hip_bf16.h>
#include <math.h>

#define B_  512
#define DM  1024
#define DI  2048
#define DS  64
#define DTR 64
#define DT  64
#define G_  8
#define E_  4
#define DC  4

typedef __bf16 bf16x8 __attribute__((ext_vector_type(8)));
typedef float  f32x4  __attribute__((ext_vector_type(4)));
typedef unsigned short ushort_t;

__device__ __forceinline__ float bf2f(__hip_bfloat16 h) { return __bfloat162float(h); }
__device__ __forceinline__ __hip_bfloat16 f2bf(float f) { return __float2bfloat16(f); }
__device__ __forceinline__ float sigmoidf_(float x){ return 1.f/(1.f+expf(-x)); }
__device__ __forceinline__ float siluf_(float x){ return x*sigmoidf_(x); }
__device__ __forceinline__ float softplusf_(float x){ return (x>20.f)? x : log1pf(expf(x)); }

__device__ __forceinline__ unsigned int pack2(float a, float b) {
  unsigned short ua = __builtin_bit_cast(unsigned short, (__bf16)a);
  unsigned short ub = __builtin_bit_cast(unsigned short, (__bf16)b);
  return (unsigned int)ua | ((unsigned int)ub << 16);
}
__device__ __forceinline__ uint4 cvt8(float4 v0, float4 v1) {
  uint4 r;
  r.x = pack2(v0.x, v0.y); r.y = pack2(v0.z, v0.w);
  r.z = pack2(v1.x, v1.y); r.w = pack2(v1.z, v1.w);
  return r;
}

enum EpiKind { EPI_PART=0, EPI_G2=1, EPI_G4=2 };

struct KParams {
  const float *uk, *tk_c, *tk_p, *W_in, *b_in, *rW, *rb, *freq, *phase, *kanW;
  const float *W_inproj, *conv_w, *conv_b, *W_x, *W_dt, *dt_bias, *W_delta, *D_skip, *W_out;
  __hip_bfloat16 *Pu, *Xs, *Sz, *Yb, *Acat;
  __hip_bfloat16 *uk_bf, *Win_bf, *Wip_bf, *Wx_bf, *Wdt128, *Wout_bf;
  float *bc, *Part, *out_hk, *out_w, *out_mask;
};

// ---- weight/activation f32 -> bf16 pre-convert (one streaming pass) ----
__device__ __forceinline__ void cvt_chunk(const float* __restrict__ s,
                                          __hip_bfloat16* __restrict__ d)
{
  float4 v0 = *reinterpret_cast<const float4*>(s);
  float4 v1 = *reinterpret_cast<const float4*>(s + 4);
  *reinterpret_cast<uint4*>(d) = cvt8(v0, v1);
}

__global__ __launch_bounds__(256)
void convert_kernel(KParams p)
{
  const int id = blockIdx.x, t = threadIdx.x;
  if (id < 256)       { size_t c = (size_t)id*256 + t;        cvt_chunk(p.uk      + c*8, p.uk_bf  + c*8); }
  else if (id < 768)  { size_t c = (size_t)(id-256)*256 + t;  cvt_chunk(p.W_in    + c*8, p.Win_bf + c*8); }
  else if (id < 2816) { size_t c = (size_t)(id-768)*256 + t;  cvt_chunk(p.W_inproj+ c*8, p.Wip_bf + c*8); }
  else if (id < 3008) { size_t c = (size_t)(id-2816)*256 + t; cvt_chunk(p.W_x     + c*8, p.Wx_bf  + c*8); }
  else if (id < 4032) { size_t c = (size_t)(id-3008)*256 + t; cvt_chunk(p.W_out   + c*8, p.Wout_bf+ c*8); }
  else {               size_t c = (size_t)(id-4032)*256 + t;  // [W_dt|W_delta] -> 2048x128
    int row = (int)(c >> 4), col0 = ((int)c & 15)*8;
    const float* s = (col0 < 64) ? (p.W_dt    + (size_t)row*64 + col0)
                                 : (p.W_delta + (size_t)row*64 + (col0-64));
    cvt_chunk(s, p.Wdt128 + (size_t)row*128 + col0);
  }
}

// C[m,n] = sum_k A[m,k]*B[n,k], all-bf16 K-contiguous operands. 256 threads =
// 4 waves (2x2), wave tile 16x32, 16x16x32 bf16 MFMA. BK=128: 96 B/thread of
// global loads per barrier interval (the compiler's vmcnt(0)-before-s_barrier
// caps in-flight bytes at one K-step's issues — BK=64 gave only 48 B and
// ~726 GB/s staging; R5->R6 -40us validated). LDS double-buffered, 52 KB.
template<int BM, int BN, int WMT, int WNT, int EK>
__device__ __forceinline__ void gemm_tile(char* smemc, int bxi, int byi, int bzi,
    const __hip_bfloat16* __restrict__ Ap, const __hip_bfloat16* __restrict__ Bp,
    float* __restrict__ Coutp, int Ka, int Kb, int kLen, int N, const KParams& p)
{
  static_assert(BM == 32*WMT && BN == 32*WNT, "2x2 wave layout");
  constexpr int BK = 128, SA = 136;             // 272B rows keep 16B align
  constexpr int NA = (BM*BK)/(256*8);
  constexpr int NB = (BN*BK)/(256*8);
  ushort_t* sA = (ushort_t*)smemc;
  ushort_t* sB = (ushort_t*)(smemc + (size_t)2*BM*SA*sizeof(ushort_t));
  const int tid  = threadIdx.x;
  const int wave = tid >> 6, lane = tid & 63;
  const int wm = wave >> 1, wn = wave & 1;
  const int r = lane & 15, q = lane >> 4;
  const int bm = byi * BM, bn = bxi * BN;
  const int kBase = bzi * kLen;
  const int T = kLen / BK;

  uint4 ua[NA], ub[NB];

  auto loadTiles = [&](int k0) {
    #pragma unroll
    for (int c=0;c<NA;++c) {
      int idx = tid*8 + c*2048; int row = idx>>7, kk = idx&127;
      ua[c] = *reinterpret_cast<const uint4*>(Ap + (size_t)(bm+row)*Ka + k0 + kk);
    }
    #pragma unroll
    for (int c=0;c<NB;++c) {
      int idx = tid*8 + c*2048; int row = idx>>7, kk = idx&127;
      ub[c] = *reinterpret_cast<const uint4*>(Bp + (size_t)(bn+row)*Kb + k0 + kk);
    }
  };
  auto writeTiles = [&](int buf) {
    #pragma unroll
    for (int c=0;c<NA;++c) {
      int idx = tid*8 + c*2048; int row = idx>>7, kk = idx&127;
      *reinterpret_cast<uint4*>(&sA[buf*(BM*SA) + row*SA + kk]) = ua[c];
    }
    #pragma unroll
    for (int c=0;c<NB;++c) {
      int idx = tid*8 + c*2048; int row = idx>>7, kk = idx&127;
      *reinterpret_cast<uint4*>(&sB[buf*(BN*SA) + row*SA + kk]) = ub[c];
    }
  };

  f32x4 acc[WMT][WNT];
  #pragma unroll
  for (int i=0;i<WMT;++i)
    #pragma unroll
    for (int j=0;j<WNT;++j) acc[i][j] = (f32x4){0.f,0.f,0.f,0.f};

  loadTiles(kBase);
  writeTiles(0);
  for (int t=0; t<T; ++t) {
    __syncthreads();
    const int cur = t & 1;
    if (t+1 < T) loadTiles(kBase + (t+1)*BK);   // overlaps MFMA below
    #pragma unroll
    for (int ks=0; ks<4; ++ks) {
      bf16x8 af[WMT], bfr[WNT];
      #pragma unroll
      for (int mt=0; mt<WMT; ++mt)
        af[mt] = *reinterpret_cast<const bf16x8*>(&sA[cur*(BM*SA) + (wm*(WMT*16)+mt*16+r)*SA + ks*32 + q*8]);
      #pragma unroll
      for (int nt=0; nt<WNT; ++nt)
        bfr[nt] = *reinterpret_cast<const bf16x8*>(&sB[cur*(BN*SA) + (wn*(WNT*16)+nt*16+r)*SA + ks*32 + q*8]);
      #pragma unroll
      for (int mt=0; mt<WMT; ++mt)
        #pragma unroll
        for (int nt=0; nt<WNT; ++nt)
          acc[mt][nt] = __builtin_amdgcn_mfma_f32_16x16x32_bf16(af[mt], bfr[nt], acc[mt][nt], 0,0,0);
    }
    if (t+1 < T) writeTiles(cur ^ 1);
  }

  #pragma unroll
  for (int mt=0; mt<WMT; ++mt) {
    #pragma unroll
    for (int nt=0; nt<WNT; ++nt) {
      #pragma unroll
      for (int i=0;i<4;++i) {
        int grow = bm + wm*(WMT*16) + mt*16 + q*4 + i;
        int gcol = bn + wn*(WNT*16) + nt*16 + r;
        float v = acc[mt][nt][i];
        if constexpr (EK == EPI_PART) {
          float* P = Coutp + (size_t)bzi * ((size_t)B_*N);
          P[(size_t)grow*N + gcol] = v;
        } else if constexpr (EK == EPI_G2) {
          if (gcol < DI) {  // x half: conv last tap + silu
            float xc = v * p.conv_w[gcol*DC + (DC-1)] + p.conv_b[gcol];
            p.Xs[(size_t)grow*DI + gcol] = f2bf(siluf_(xc));
          } else {          // z half: silu(z)
            p.Sz[(size_t)grow*DI + (gcol - DI)] = f2bf(siluf_(v));
          }
        } else {            // EPI_G4
          float dt  = softplusf_(v + p.dt_bias[gcol]);
          float xsv = bf2f(p.Xs[(size_t)grow*DI + gcol]);
          float szv = bf2f(p.Sz[(size_t)grow*DI + gcol]);
          float y = (dt * xsv * p.bc[grow] + p.D_skip[gcol] * xsv) * szv;
          p.Yb[(size_t)grow*DI + gcol] = f2bf(y);
        }
      }
    }
  }
}

// ---- routing / kan ----

__device__ __forceinline__ void route(float t, const float* rW, const float* rb,
                                      float* w, float* mask, float* wn)
{
  float l[E_];
  float m = -1e30f;
  for (int e=0;e<E_;++e){ l[e] = t*rW[e] + rb[e]; m = fmaxf(m, l[e]); }
  float s = 0.f;
  for (int e=0;e<E_;++e){ w[e] = expf(l[e]-m); s += w[e]; }
  for (int e=0;e<E_;++e) w[e] /= s;
  int i1 = 0;
  for (int e=1;e<E_;++e) if (w[e] > w[i1]) i1 = e;
  int i2 = -1;
  for (int e=0;e<E_;++e) if (e != i1 && (i2 < 0 || w[e] > w[i2])) i2 = e;
  float ssel = w[i1] + w[i2] + 1e-8f;
  for (int e=0;e<E_;++e){
    float mk = (e==i1 || e==i2) ? 1.f : 0.f;
    mask[e] = mk;
    wn[e] = mk * w[e] / ssel;
  }
}

// One job = 4 batch rows, one per wave. R6's 50us straggler was this job's
// kanW dot: lane-strided (2KB apart) gathers = 64-segment uncoalesced loads,
// L2-cold after workspace fills (~1000cyc each x128 ~= 50us). Fix: stage kanW
// into LDS in 4 coalesced 32KB j-window chunks (rows padded to 132 floats to
// break the 512B-stride bank pattern), dot from LDS.
__device__ __forceinline__ void kan_job(char* smemc, int job, const KParams& p)
{
  float* dphi   = (float*)smemc;                // 4 waves x 512 floats = 8 KB
  float* kchunk = dphi + 4*512;                 // 64 rows x 132 floats = 33 KB
  const int tid = threadIdx.x;
  const int wv = tid >> 6, lane = tid & 63;
  const int b = job*4 + wv;
  {
    float t  = p.tk_c[b];
    float tp = p.tk_p[b];
    float w_c[E_], mk_c[E_], wn_c[E_];
    float w_p[E_], mk_p[E_], wn_p[E_];
    route(t,  p.rW, p.rb, w_c, mk_c, wn_c);
    route(tp, p.rW, p.rb, w_p, mk_p, wn_p);
    if (lane < E_) {
      p.out_w[b*E_ + lane]    = w_c[lane];
      p.out_mask[b*E_ + lane] = mk_c[lane];
    }
    float ec = 0.f, epv = 0.f;
    #pragma unroll
    for (int e=0;e<E_;++e) {
      float f  = p.freq[e*DT + lane];
      float ph = p.phase[e*DT + lane];
      ec  += wn_c[e] * sinf(t*f + ph);
      epv += wn_p[e] * sinf(tp*f + ph);
    }
    const float h = 2.f/(G_-1);
    #pragma unroll
    for (int g=0; g<G_; ++g) {
      float gr = -1.f + g*h;
      float a  = (ec - gr)/h;
      float bb = (epv - gr)/h;
      dphi[wv*512 + lane*G_ + g] = expf(-a*a) - expf(-bb*bb);
    }
  }

  float accv = 0.f;
  #pragma unroll
  for (int c=0;c<4;++c) {                       // j-window = 128 floats
    __syncthreads();                            // dphi ready (c=0) / kchunk reuse
    {                                           // stage: 64 rows x 512B, coalesced
      const int rr = tid >> 2, seg = tid & 3;
      const float* src = p.kanW + (size_t)rr*512 + c*128 + seg*32;
      float* dst = kchunk + rr*132 + seg*32;
      #pragma unroll
      for (int i=0;i<8;++i)
        *reinterpret_cast<float4*>(dst + i*4) = *reinterpret_cast<const float4*>(src + i*4);
    }
    __syncthreads();
    const float* kr = kchunk + lane*132;        // lane's output row
    const float* dd = dphi + wv*512 + c*128;
    #pragma unroll
    for (int j=0;j<128;j+=4) {
      float4 kv = *reinterpret_cast<const float4*>(kr + j);
      float4 dv = *reinterpret_cast<const float4*>(dd + j);
      accv += kv.x*dv.x + kv.y*dv.y + kv.z*dv.z + kv.w*dv.w;
    }
  }
  p.Acat[b*128 + 64 + lane] = f2bf(accv);
}

// ---- kernels (one symbol per stage so rocprof top-5 identifies the stage) ----

#define GEMM_SMEM(BM,BN) ((2*(BM)*136 + 2*(BN)*136)*2)

// K1: mote/kan (ids 0-127, dispatched FIRST: it's the long pole, overlap it
// with G1) + G1 split-K x4 (ids 128-1151).
__global__ __launch_bounds__(256)
void g1kan_kernel(KParams p)
{
  __shared__ __align__(16) char smem[GEMM_SMEM(32,64)];   // 52224 B (kan uses 42KB)
  const int id = blockIdx.x;
  if (id < 128) {
    kan_job(smem, id, p);
  } else {
    const int id2 = id - 128;
    const int bxi = id2 & 15, byi = (id2 >> 4) & 15, bzi = id2 >> 8;
    gemm_tile<32,64,1,2,EPI_PART>(smem, bxi, byi, bzi,
        p.uk_bf, p.Win_bf, p.Part, DM, DM, 256, DM, p);
  }
}

// G2: xz = pu @ W_inproj^T (512x4096x1024), conv+silu / silu fused. 1024 wgs.
__global__ __launch_bounds__(256)
void g2_kernel(KParams p)
{
  __shared__ __align__(16) char smem[GEMM_SMEM(32,64)];
  const int bxi = blockIdx.x & 63, byi = blockIdx.x >> 6;
  gemm_tile<32,64,1,2,EPI_G2>(smem, bxi, byi, 0, p.Pu, p.Wip_bf, nullptr, DM, DM, DM, 2*DI, p);
}

// G3: x_dbl = xs @ W_x^T (512x192x2048), split-K x8 -> partials. 384 wgs.
__global__ __launch_bounds__(256)
void g3_kernel(KParams p)
{
  __shared__ __align__(16) char smem[GEMM_SMEM(32,64)];
  const int bxi = blockIdx.x % 3, rem = blockIdx.x / 3;
  const int byi = rem & 15, bzi = rem >> 4;
  gemm_tile<32,64,1,2,EPI_PART>(smem, bxi, byi, bzi, p.Xs, p.Wx_bf, p.Part, DI, DI, 256, 192, p);
}

// G4: dt GEMM (512x2048x128, B=Wdt128) + softplus + y fusion. 512 wgs.
__global__ __launch_bounds__(256)
void g4_kernel(KParams p)
{
  __shared__ __align__(16) char smem[GEMM_SMEM(32,64)];
  const int bxi = blockIdx.x & 31, byi = blockIdx.x >> 5;
  gemm_tile<32,64,1,2,EPI_G4>(smem, bxi, byi, 0, p.Acat, p.Wdt128, nullptr, 128, 128, 128, DI, p);
}

// G5: hk = y @ W_out^T (512x1024x2048), split-K x4 -> partials. 1024 wgs.
__global__ __launch_bounds__(256)
void g5_kernel(KParams p)
{
  __shared__ __align__(16) char smem[GEMM_SMEM(32,64)];
  const int bxi = blockIdx.x & 15, rem = blockIdx.x >> 4;
  const int byi = rem & 15, bzi = rem >> 4;
  gemm_tile<32,64,1,2,EPI_PART>(smem, bxi, byi, bzi, p.Yb, p.Wout_bf, p.Part, DI, DI, 512, DM, p);
}

// Pu = f2bf(sum_{s<4} part[s] + bias)
__global__ __launch_bounds__(256)
void reduce_bias_kernel(KParams p)
{
  const int i = blockIdx.x*256 + threadIdx.x;       // float4 index
  const int total = B_*DM/4;
  const float4* pp = (const float4*)p.Part;
  float4 s = pp[i];
  #pragma unroll
  for (int k=1;k<4;++k){ float4 t = pp[i + k*total]; s.x+=t.x; s.y+=t.y; s.z+=t.z; s.w+=t.w; }
  float4 bv = ((const float4*)p.b_in)[i & (DM/4 - 1)];
  uint2 o; o.x = pack2(s.x+bv.x, s.y+bv.y); o.y = pack2(s.z+bv.z, s.w+bv.w);
  ((uint2*)p.Pu)[i] = o;
}

// x_dbl reduce (8 splits): col<64 -> Acat[:,0:64] bf16 (dt_r); cols 64..191
// are B,C — stash in LDS, bc[row] = dot(B,C) via wave reduce. One row per wg.
__global__ __launch_bounds__(192)
void reduce_g3_kernel(KParams p)
{
  const int row = blockIdx.x, col = threadIdx.x;    // 192 threads
  const int stride = B_*192;
  float s = 0.f;
  #pragma unroll
  for (int k=0;k<8;++k) s += p.Part[(size_t)k*stride + row*192 + col];
  __shared__ float sBC[128];
  if (col < 64) p.Acat[row*128 + col] = f2bf(s);
  else          sBC[col-64] = s;
  __syncthreads();
  if (col < 64) {
    float pval = sBC[col] * sBC[col+64];
    #pragma unroll
    for (int off=32; off; off>>=1) pval += __shfl_down(pval, off);
    if (col == 0) p.bc[row] = pval;
  }
}

// hk = sum_{s<4} part[s]  (f32 out)
__global__ __launch_bounds__(256)
void reduce_plain_kernel(KParams p)
{
  const int i = blockIdx.x*256 + threadIdx.x;
  const int total = B_*DM/4;
  const float4* pp = (const float4*)p.Part;
  float4 s = pp[i];
  #pragma unroll
  for (int k=1;k<4;++k){ float4 t = pp[i + k*total]; s.x+=t.x; s.y+=t.y; s.z+=t.z; s.w+=t.w; }
  ((float4*)p.out_hk)[i] = s;
}

extern "C" void kernel_launch(void* const* d_in, const int* in_sizes, int n_in,
                              void* d_out, int out_size, void* d_ws, size_t ws_size,
                              hipStream_t stream)
{
  KParams p;
  p.uk       = (const float*)d_in[0];
  p.tk_c     = (const float*)d_in[1];
  p.tk_p     = (const float*)d_in[2];
  p.W_in     = (const float*)d_in[3];
  p.b_in     = (const float*)d_in[4];
  p.rW       = (const float*)d_in[5];
  p.rb       = (const float*)d_in[6];
  p.freq     = (const float*)d_in[7];
  p.phase    = (const float*)d_in[8];
  p.kanW     = (const float*)d_in[9];
  p.W_inproj = (const float*)d_in[10];
  p.conv_w   = (const float*)d_in[11];
  p.conv_b   = (const float*)d_in[12];
  p.W_x      = (const float*)d_in[13];
  p.W_dt     = (const float*)d_in[14];
  p.dt_bias  = (const float*)d_in[15];
  p.W_delta  = (const float*)d_in[16];
  p.D_skip   = (const float*)d_in[18];
  p.W_out    = (const float*)d_in[19];

  char* ws = (char*)d_ws;
  p.Pu     = (__hip_bfloat16*)(ws);                                // 1 MB
  p.Xs     = (__hip_bfloat16*)(ws + (size_t)(1<<20));              // 2 MB
  p.Sz     = (__hip_bfloat16*)(ws + (size_t)3*(1<<20));            // 2 MB
  p.Yb     = (__hip_bfloat16*)(ws + (size_t)5*(1<<20));            // 2 MB
  p.Acat   = (__hip_bfloat16*)(ws + (size_t)7*(1<<20));            // 128 KB
  p.bc     = (float*)         (ws + (size_t)7*(1<<20) + (128<<10));// 2 KB
  p.Part   = (float*)         (ws + (size_t)8*(1<<20));            // 8 MB
  p.uk_bf  = (__hip_bfloat16*)(ws + (size_t)16*(1<<20));           // 1 MB
  p.Win_bf = (__hip_bfloat16*)(ws + (size_t)17*(1<<20));           // 2 MB
  p.Wip_bf = (__hip_bfloat16*)(ws + (size_t)19*(1<<20));           // 8 MB
  p.Wx_bf  = (__hip_bfloat16*)(ws + (size_t)27*(1<<20));           // 768 KB
  p.Wdt128 = (__hip_bfloat16*)(ws + (size_t)28*(1<<20));           // 512 KB
  p.Wout_bf= (__hip_bfloat16*)(ws + (size_t)29*(1<<20));           // 4 MB

  p.out_hk   = (float*)d_out;
  p.out_w    = p.out_hk + (size_t)B_*DM;
  p.out_mask = p.out_w  + (size_t)B_*E_;

  // K0: f32 -> bf16 pre-convert of uk + all GEMM B operands (one pass)
  convert_kernel<<<dim3(4160), 256, 0, stream>>>(p);

  // K1: kan (ids 0-127, first = overlaps G1) + G1 split-K x4 (1024 wgs)
  g1kan_kernel<<<dim3(1152), 256, 0, stream>>>(p);
  reduce_bias_kernel<<<dim3(512), 256, 0, stream>>>(p);

  // G2
  g2_kernel<<<dim3(1024), 256, 0, stream>>>(p);

  // G3 + reduce
  g3_kernel<<<dim3(384), 256, 0, stream>>>(p);
  reduce_g3_kernel<<<dim3(512), 192, 0, stream>>>(p);

  // G4
  g4_kernel<<<dim3(512), 256, 0, stream>>>(p);

  // G5 + reduce
  g5_kernel<<<dim3(1024), 256, 0, stream>>>(p);
  reduce_plain_kernel<<<dim3(512), 256, 0, stream>>>(p);
}

// Round 9
// 169.122 us; speedup vs baseline: 1.3308x; 1.0402x over previous
//
#include <hip/hip_runtime.h>
#include <hip/hip_bf16.h>
#include <math.h>

#define B_  512
#define DM  1024
#define DI  2048
#define DS  64
#define DTR 64
#define DT  64
#define G_  8
#define E_  4
#define DC  4

typedef __bf16 bf16x8 __attribute__((ext_vector_type(8)));
typedef float  f32x4  __attribute__((ext_vector_type(4)));
typedef unsigned short ushort_t;

__device__ __forceinline__ float bf2f(__hip_bfloat16 h) { return __bfloat162float(h); }
__device__ __forceinline__ __hip_bfloat16 f2bf(float f) { return __float2bfloat16(f); }
__device__ __forceinline__ float sigmoidf_(float x){ return 1.f/(1.f+expf(-x)); }
__device__ __forceinline__ float siluf_(float x){ return x*sigmoidf_(x); }
__device__ __forceinline__ float softplusf_(float x){ return (x>20.f)? x : log1pf(expf(x)); }

__device__ __forceinline__ unsigned int pack2(float a, float b) {
  unsigned short ua = __builtin_bit_cast(unsigned short, (__bf16)a);
  unsigned short ub = __builtin_bit_cast(unsigned short, (__bf16)b);
  return (unsigned int)ua | ((unsigned int)ub << 16);
}
__device__ __forceinline__ uint4 cvt8(float4 v0, float4 v1) {
  uint4 r;
  r.x = pack2(v0.x, v0.y); r.y = pack2(v0.z, v0.w);
  r.z = pack2(v1.x, v1.y); r.w = pack2(v1.z, v1.w);
  return r;
}

enum EpiKind { EPI_PART=0, EPI_G2=1, EPI_G4=2 };

struct KParams {
  const float *uk, *tk_c, *tk_p, *W_in, *b_in, *rW, *rb, *freq, *phase, *kanW;
  const float *W_inproj, *conv_w, *conv_b, *W_x, *W_dt, *dt_bias, *W_delta, *D_skip, *W_out;
  __hip_bfloat16 *Pu, *Xs, *Sz, *Yb, *Acat;
  __hip_bfloat16 *Wip_bf, *Wx_bf, *Wdt128, *Wout_bf;
  float *bc, *Part, *out_hk, *out_w, *out_mask;
};

// ---- weight f32 -> bf16 convert helper ----
__device__ __forceinline__ void cvt_chunk(const float* __restrict__ s,
                                          __hip_bfloat16* __restrict__ d)
{
  float4 v0 = *reinterpret_cast<const float4*>(s);
  float4 v1 = *reinterpret_cast<const float4*>(s + 4);
  *reinterpret_cast<uint4*>(d) = cvt8(v0, v1);
}

// C[m,n] = sum_k A[m,k]*B[n,k], K-contiguous operands (bf16, or f32 with
// on-the-fly cvt when CVTA/CVTB). 256 threads = 4 waves (2x2), wave tile
// 16x32, 16x16x32 bf16 MFMA. BK=128: >=96 B/thread of global loads per
// barrier interval (compiler's vmcnt(0)-before-s_barrier caps in-flight
// bytes at one K-step's issues — BK=64 bf16 gave 48 B and ~726 GB/s, R5;
// BK=128 validated R5->R6 -40us; f32 sources at BK=128 issue 192 B/thread).
template<int BM, int BN, int WMT, int WNT, int EK, bool CVTA, bool CVTB>
__device__ __forceinline__ void gemm_tile(char* smemc, int bxi, int byi, int bzi,
    const void* __restrict__ Ap, const void* __restrict__ Bp,
    float* __restrict__ Coutp, int Ka, int Kb, int kLen, int N, const KParams& p)
{
  static_assert(BM == 32*WMT && BN == 32*WNT, "2x2 wave layout");
  constexpr int BK = 128, SA = 136;             // 272B rows keep 16B align
  constexpr int NA = (BM*BK)/(256*8);
  constexpr int NB = (BN*BK)/(256*8);
  ushort_t* sA = (ushort_t*)smemc;
  ushort_t* sB = (ushort_t*)(smemc + (size_t)2*BM*SA*sizeof(ushort_t));
  const int tid  = threadIdx.x;
  const int wave = tid >> 6, lane = tid & 63;
  const int wm = wave >> 1, wn = wave & 1;
  const int r = lane & 15, q = lane >> 4;
  const int bm = byi * BM, bn = bxi * BN;
  const int kBase = bzi * kLen;
  const int T = kLen / BK;

  uint4 ua[NA], ub[NB];
  float4 fa[NA][2], fb[NB][2];

  auto loadTiles = [&](int k0) {
    #pragma unroll
    for (int c=0;c<NA;++c) {
      int idx = tid*8 + c*2048; int row = idx>>7, kk = idx&127;
      if constexpr (CVTA) {
        const float* s = (const float*)Ap + (size_t)(bm+row)*Ka + k0 + kk;
        fa[c][0] = *reinterpret_cast<const float4*>(s);
        fa[c][1] = *reinterpret_cast<const float4*>(s+4);
      } else {
        ua[c] = *reinterpret_cast<const uint4*>((const __hip_bfloat16*)Ap + (size_t)(bm+row)*Ka + k0 + kk);
      }
    }
    #pragma unroll
    for (int c=0;c<NB;++c) {
      int idx = tid*8 + c*2048; int row = idx>>7, kk = idx&127;
      if constexpr (CVTB) {
        const float* s = (const float*)Bp + (size_t)(bn+row)*Kb + k0 + kk;
        fb[c][0] = *reinterpret_cast<const float4*>(s);
        fb[c][1] = *reinterpret_cast<const float4*>(s+4);
      } else {
        ub[c] = *reinterpret_cast<const uint4*>((const __hip_bfloat16*)Bp + (size_t)(bn+row)*Kb + k0 + kk);
      }
    }
  };
  auto writeTiles = [&](int buf) {
    #pragma unroll
    for (int c=0;c<NA;++c) {
      int idx = tid*8 + c*2048; int row = idx>>7, kk = idx&127;
      uint4 v; if constexpr (CVTA) v = cvt8(fa[c][0], fa[c][1]); else v = ua[c];
      *reinterpret_cast<uint4*>(&sA[buf*(BM*SA) + row*SA + kk]) = v;
    }
    #pragma unroll
    for (int c=0;c<NB;++c) {
      int idx = tid*8 + c*2048; int row = idx>>7, kk = idx&127;
      uint4 v; if constexpr (CVTB) v = cvt8(fb[c][0], fb[c][1]); else v = ub[c];
      *reinterpret_cast<uint4*>(&sB[buf*(BN*SA) + row*SA + kk]) = v;
    }
  };

  f32x4 acc[WMT][WNT];
  #pragma unroll
  for (int i=0;i<WMT;++i)
    #pragma unroll
    for (int j=0;j<WNT;++j) acc[i][j] = (f32x4){0.f,0.f,0.f,0.f};

  loadTiles(kBase);
  writeTiles(0);
  for (int t=0; t<T; ++t) {
    __syncthreads();
    const int cur = t & 1;
    if (t+1 < T) loadTiles(kBase + (t+1)*BK);   // overlaps MFMA below
    #pragma unroll
    for (int ks=0; ks<4; ++ks) {
      bf16x8 af[WMT], bfr[WNT];
      #pragma unroll
      for (int mt=0; mt<WMT; ++mt)
        af[mt] = *reinterpret_cast<const bf16x8*>(&sA[cur*(BM*SA) + (wm*(WMT*16)+mt*16+r)*SA + ks*32 + q*8]);
      #pragma unroll
      for (int nt=0; nt<WNT; ++nt)
        bfr[nt] = *reinterpret_cast<const bf16x8*>(&sB[cur*(BN*SA) + (wn*(WNT*16)+nt*16+r)*SA + ks*32 + q*8]);
      #pragma unroll
      for (int mt=0; mt<WMT; ++mt)
        #pragma unroll
        for (int nt=0; nt<WNT; ++nt)
          acc[mt][nt] = __builtin_amdgcn_mfma_f32_16x16x32_bf16(af[mt], bfr[nt], acc[mt][nt], 0,0,0);
    }
    if (t+1 < T) writeTiles(cur ^ 1);
  }

  #pragma unroll
  for (int mt=0; mt<WMT; ++mt) {
    #pragma unroll
    for (int nt=0; nt<WNT; ++nt) {
      #pragma unroll
      for (int i=0;i<4;++i) {
        int grow = bm + wm*(WMT*16) + mt*16 + q*4 + i;
        int gcol = bn + wn*(WNT*16) + nt*16 + r;
        float v = acc[mt][nt][i];
        if constexpr (EK == EPI_PART) {
          float* P = Coutp + (size_t)bzi * ((size_t)B_*N);
          P[(size_t)grow*N + gcol] = v;
        } else if constexpr (EK == EPI_G2) {
          if (gcol < DI) {  // x half: conv last tap + silu
            float xc = v * p.conv_w[gcol*DC + (DC-1)] + p.conv_b[gcol];
            p.Xs[(size_t)grow*DI + gcol] = f2bf(siluf_(xc));
          } else {          // z half: silu(z)
            p.Sz[(size_t)grow*DI + (gcol - DI)] = f2bf(siluf_(v));
          }
        } else {            // EPI_G4
          float dt  = softplusf_(v + p.dt_bias[gcol]);
          float xsv = bf2f(p.Xs[(size_t)grow*DI + gcol]);
          float szv = bf2f(p.Sz[(size_t)grow*DI + gcol]);
          float y = (dt * xsv * p.bc[grow] + p.D_skip[gcol] * xsv) * szv;
          p.Yb[(size_t)grow*DI + gcol] = f2bf(y);
        }
      }
    }
  }
}

// ---- routing / kan ----

__device__ __forceinline__ void route(float t, const float* rW, const float* rb,
                                      float* w, float* mask, float* wn)
{
  float l[E_];
  float m = -1e30f;
  for (int e=0;e<E_;++e){ l[e] = t*rW[e] + rb[e]; m = fmaxf(m, l[e]); }
  float s = 0.f;
  for (int e=0;e<E_;++e){ w[e] = expf(l[e]-m); s += w[e]; }
  for (int e=0;e<E_;++e) w[e] /= s;
  int i1 = 0;
  for (int e=1;e<E_;++e) if (w[e] > w[i1]) i1 = e;
  int i2 = -1;
  for (int e=0;e<E_;++e) if (e != i1 && (i2 < 0 || w[e] > w[i2])) i2 = e;
  float ssel = w[i1] + w[i2] + 1e-8f;
  for (int e=0;e<E_;++e){
    float mk = (e==i1 || e==i2) ? 1.f : 0.f;
    mask[e] = mk;
    wn[e] = mk * w[e] / ssel;
  }
}

// One job = 4 batch rows, one per wave. kanW dot staged through LDS in 4
// coalesced 32KB j-window chunks (rows padded to 132 floats vs bank stride)
// — R6's 50us uncoalesced-gather straggler fixed this way (R7: -9us dur).
__device__ __forceinline__ void kan_job(char* smemc, int job, const KParams& p)
{
  float* dphi   = (float*)smemc;                // 4 waves x 512 floats = 8 KB
  float* kchunk = dphi + 4*512;                 // 64 rows x 132 floats = 33 KB
  const int tid = threadIdx.x;
  const int wv = tid >> 6, lane = tid & 63;
  const int b = job*4 + wv;
  {
    float t  = p.tk_c[b];
    float tp = p.tk_p[b];
    float w_c[E_], mk_c[E_], wn_c[E_];
    float w_p[E_], mk_p[E_], wn_p[E_];
    route(t,  p.rW, p.rb, w_c, mk_c, wn_c);
    route(tp, p.rW, p.rb, w_p, mk_p, wn_p);
    if (lane < E_) {
      p.out_w[b*E_ + lane]    = w_c[lane];
      p.out_mask[b*E_ + lane] = mk_c[lane];
    }
    float ec = 0.f, epv = 0.f;
    #pragma unroll
    for (int e=0;e<E_;++e) {
      float f  = p.freq[e*DT + lane];
      float ph = p.phase[e*DT + lane];
      ec  += wn_c[e] * sinf(t*f + ph);
      epv += wn_p[e] * sinf(tp*f + ph);
    }
    const float h = 2.f/(G_-1);
    #pragma unroll
    for (int g=0; g<G_; ++g) {
      float gr = -1.f + g*h;
      float a  = (ec - gr)/h;
      float bb = (epv - gr)/h;
      dphi[wv*512 + lane*G_ + g] = expf(-a*a) - expf(-bb*bb);
    }
  }

  float accv = 0.f;
  #pragma unroll
  for (int c=0;c<4;++c) {                       // j-window = 128 floats
    __syncthreads();                            // dphi ready (c=0) / kchunk reuse
    {                                           // stage: 64 rows x 512B, coalesced
      const int rr = tid >> 2, seg = tid & 3;
      const float* src = p.kanW + (size_t)rr*512 + c*128 + seg*32;
      float* dst = kchunk + rr*132 + seg*32;
      #pragma unroll
      for (int i=0;i<8;++i)
        *reinterpret_cast<float4*>(dst + i*4) = *reinterpret_cast<const float4*>(src + i*4);
    }
    __syncthreads();
    const float* kr = kchunk + lane*132;        // lane's output row
    const float* dd = dphi + wv*512 + c*128;
    #pragma unroll
    for (int j=0;j<128;j+=4) {
      float4 kv = *reinterpret_cast<const float4*>(kr + j);
      float4 dv = *reinterpret_cast<const float4*>(dd + j);
      accv += kv.x*dv.x + kv.y*dv.y + kv.z*dv.z + kv.w*dv.w;
    }
  }
  p.Acat[b*128 + 64 + lane] = f2bf(accv);
}

// ---- kernels (one symbol per stage so rocprof top-5 identifies the stage) ----

#define GEMM_SMEM(BM,BN) ((2*(BM)*136 + 2*(BN)*136)*2)

// K1: three disjoint block ranges in ONE launch:
//   ids [0,128)      kan (long pole, first)
//   ids [128,1152)   G1 split-K x4, f32 uk/W_in direct (192 B/thread issue)
//   ids [1152,4544)  weight converts for LATER stages (Wip/Wx/Wout/Wdt128) —
//                    G2+ consume them, the kernel boundary is the fence.
__global__ __launch_bounds__(256)
void g1kan_conv_kernel(KParams p)
{
  __shared__ __align__(16) char smem[GEMM_SMEM(32,64)];   // 52224 B
  const int id = blockIdx.x, t = threadIdx.x;
  if (id < 128) {
    kan_job(smem, id, p);
  } else if (id < 1152) {
    const int id2 = id - 128;
    const int bxi = id2 & 15, byi = (id2 >> 4) & 15, bzi = id2 >> 8;
    gemm_tile<32,64,1,2,EPI_PART,true,true>(smem, bxi, byi, bzi,
        p.uk, p.W_in, p.Part, DM, DM, 256, DM, p);
  } else if (id < 3200) { size_t c = (size_t)(id-1152)*256 + t; cvt_chunk(p.W_inproj + c*8, p.Wip_bf  + c*8); }
  else if (id < 3392)   { size_t c = (size_t)(id-3200)*256 + t; cvt_chunk(p.W_x      + c*8, p.Wx_bf   + c*8); }
  else if (id < 4416)   { size_t c = (size_t)(id-3392)*256 + t; cvt_chunk(p.W_out    + c*8, p.Wout_bf + c*8); }
  else {                  size_t c = (size_t)(id-4416)*256 + t; // [W_dt|W_delta] -> 2048x128
    int row = (int)(c >> 4), col0 = ((int)c & 15)*8;
    const float* s = (col0 < 64) ? (p.W_dt    + (size_t)row*64 + col0)
                                 : (p.W_delta + (size_t)row*64 + (col0-64));
    cvt_chunk(s, p.Wdt128 + (size_t)row*128 + col0);
  }
}

// G2: xz = pu @ W_inproj^T (512x4096x1024), conv+silu / silu fused. 1024 wgs.
__global__ __launch_bounds__(256)
void g2_kernel(KParams p)
{
  __shared__ __align__(16) char smem[GEMM_SMEM(32,64)];
  const int bxi = blockIdx.x & 63, byi = blockIdx.x >> 6;
  gemm_tile<32,64,1,2,EPI_G2,false,false>(smem, bxi, byi, 0, p.Pu, p.Wip_bf, nullptr, DM, DM, DM, 2*DI, p);
}

// G3: x_dbl = xs @ W_x^T (512x192x2048), split-K x8 -> partials. 384 wgs.
__global__ __launch_bounds__(256)
void g3_kernel(KParams p)
{
  __shared__ __align__(16) char smem[GEMM_SMEM(32,64)];
  const int bxi = blockIdx.x % 3, rem = blockIdx.x / 3;
  const int byi = rem & 15, bzi = rem >> 4;
  gemm_tile<32,64,1,2,EPI_PART,false,false>(smem, bxi, byi, bzi, p.Xs, p.Wx_bf, p.Part, DI, DI, 256, 192, p);
}

// G4: dt GEMM (512x2048x128, B=Wdt128) + softplus + y fusion. 512 wgs.
__global__ __launch_bounds__(256)
void g4_kernel(KParams p)
{
  __shared__ __align__(16) char smem[GEMM_SMEM(32,64)];
  const int bxi = blockIdx.x & 31, byi = blockIdx.x >> 5;
  gemm_tile<32,64,1,2,EPI_G4,false,false>(smem, bxi, byi, 0, p.Acat, p.Wdt128, nullptr, 128, 128, 128, DI, p);
}

// G5: hk = y @ W_out^T (512x1024x2048), split-K x4 -> partials. 1024 wgs.
__global__ __launch_bounds__(256)
void g5_kernel(KParams p)
{
  __shared__ __align__(16) char smem[GEMM_SMEM(32,64)];
  const int bxi = blockIdx.x & 15, rem = blockIdx.x >> 4;
  const int byi = rem & 15, bzi = rem >> 4;
  gemm_tile<32,64,1,2,EPI_PART,false,false>(smem, bxi, byi, bzi, p.Yb, p.Wout_bf, p.Part, DI, DI, 512, DM, p);
}

// Pu = f2bf(sum_{s<4} part[s] + bias)
__global__ __launch_bounds__(256)
void reduce_bias_kernel(KParams p)
{
  const int i = blockIdx.x*256 + threadIdx.x;       // float4 index
  const int total = B_*DM/4;
  const float4* pp = (const float4*)p.Part;
  float4 s = pp[i];
  #pragma unroll
  for (int k=1;k<4;++k){ float4 t = pp[i + k*total]; s.x+=t.x; s.y+=t.y; s.z+=t.z; s.w+=t.w; }
  float4 bv = ((const float4*)p.b_in)[i & (DM/4 - 1)];
  uint2 o; o.x = pack2(s.x+bv.x, s.y+bv.y); o.y = pack2(s.z+bv.z, s.w+bv.w);
  ((uint2*)p.Pu)[i] = o;
}

// x_dbl reduce (8 splits): col<64 -> Acat[:,0:64] bf16 (dt_r); cols 64..191
// are B,C — stash in LDS, bc[row] = dot(B,C) via wave reduce. One row per wg.
__global__ __launch_bounds__(192)
void reduce_g3_kernel(KParams p)
{
  const int row = blockIdx.x, col = threadIdx.x;    // 192 threads
  const int stride = B_*192;
  float s = 0.f;
  #pragma unroll
  for (int k=0;k<8;++k) s += p.Part[(size_t)k*stride + row*192 + col];
  __shared__ float sBC[128];
  if (col < 64) p.Acat[row*128 + col] = f2bf(s);
  else          sBC[col-64] = s;
  __syncthreads();
  if (col < 64) {
    float pval = sBC[col] * sBC[col+64];
    #pragma unroll
    for (int off=32; off; off>>=1) pval += __shfl_down(pval, off);
    if (col == 0) p.bc[row] = pval;
  }
}

// hk = sum_{s<4} part[s]  (f32 out)
__global__ __launch_bounds__(256)
void reduce_plain_kernel(KParams p)
{
  const int i = blockIdx.x*256 + threadIdx.x;
  const int total = B_*DM/4;
  const float4* pp = (const float4*)p.Part;
  float4 s = pp[i];
  #pragma unroll
  for (int k=1;k<4;++k){ float4 t = pp[i + k*total]; s.x+=t.x; s.y+=t.y; s.z+=t.z; s.w+=t.w; }
  ((float4*)p.out_hk)[i] = s;
}

extern "C" void kernel_launch(void* const* d_in, const int* in_sizes, int n_in,
                              void* d_out, int out_size, void* d_ws, size_t ws_size,
                              hipStream_t stream)
{
  KParams p;
  p.uk       = (const float*)d_in[0];
  p.tk_c     = (const float*)d_in[1];
  p.tk_p     = (const float*)d_in[2];
  p.W_in     = (const float*)d_in[3];
  p.b_in     = (const float*)d_in[4];
  p.rW       = (const float*)d_in[5];
  p.rb       = (const float*)d_in[6];
  p.freq     = (const float*)d_in[7];
  p.phase    = (const float*)d_in[8];
  p.kanW     = (const float*)d_in[9];
  p.W_inproj = (const float*)d_in[10];
  p.conv_w   = (const float*)d_in[11];
  p.conv_b   = (const float*)d_in[12];
  p.W_x      = (const float*)d_in[13];
  p.W_dt     = (const float*)d_in[14];
  p.dt_bias  = (const float*)d_in[15];
  p.W_delta  = (const float*)d_in[16];
  p.D_skip   = (const float*)d_in[18];
  p.W_out    = (const float*)d_in[19];

  char* ws = (char*)d_ws;
  p.Pu     = (__hip_bfloat16*)(ws);                                // 1 MB
  p.Xs     = (__hip_bfloat16*)(ws + (size_t)(1<<20));              // 2 MB
  p.Sz     = (__hip_bfloat16*)(ws + (size_t)3*(1<<20));            // 2 MB
  p.Yb     = (__hip_bfloat16*)(ws + (size_t)5*(1<<20));            // 2 MB
  p.Acat   = (__hip_bfloat16*)(ws + (size_t)7*(1<<20));            // 128 KB
  p.bc     = (float*)         (ws + (size_t)7*(1<<20) + (128<<10));// 2 KB
  p.Part   = (float*)         (ws + (size_t)8*(1<<20));            // 8 MB
  p.Wip_bf = (__hip_bfloat16*)(ws + (size_t)19*(1<<20));           // 8 MB
  p.Wx_bf  = (__hip_bfloat16*)(ws + (size_t)27*(1<<20));           // 768 KB
  p.Wdt128 = (__hip_bfloat16*)(ws + (size_t)28*(1<<20));           // 512 KB
  p.Wout_bf= (__hip_bfloat16*)(ws + (size_t)29*(1<<20));           // 4 MB

  p.out_hk   = (float*)d_out;
  p.out_w    = p.out_hk + (size_t)B_*DM;
  p.out_mask = p.out_w  + (size_t)B_*E_;

  // K1: kan + G1 (f32 direct) + weight converts, one launch (disjoint ranges)
  g1kan_conv_kernel<<<dim3(4544), 256, 0, stream>>>(p);
  reduce_bias_kernel<<<dim3(512), 256, 0, stream>>>(p);

  // G2
  g2_kernel<<<dim3(1024), 256, 0, stream>>>(p);

  // G3 + reduce
  g3_kernel<<<dim3(384), 256, 0, stream>>>(p);
  reduce_g3_kernel<<<dim3(512), 192, 0, stream>>>(p);

  // G4
  g4_kernel<<<dim3(512), 256, 0, stream>>>(p);

  // G5 + reduce
  g5_kernel<<<dim3(1024), 256, 0, stream>>>(p);
  reduce_plain_kernel<<<dim3(512), 256, 0, stream>>>(p);
}

// Round 10
// 168.976 us; speedup vs baseline: 1.3320x; 1.0009x over previous
//
#include <hip/hip_runtime.h>
#include <hip/hip_bf16.h>
#include <math.h>

#define B_  512
#define DM  1024
#define DI  2048
#define DS  64
#define DTR 64
#define DT  64
#define G_  8
#define E_  4
#define DC  4

typedef __bf16 bf16x8 __attribute__((ext_vector_type(8)));
typedef float  f32x4  __attribute__((ext_vector_type(4)));
typedef unsigned short ushort_t;

__device__ __forceinline__ float bf2f(__hip_bfloat16 h) { return __bfloat162float(h); }
__device__ __forceinline__ __hip_bfloat16 f2bf(float f) { return __float2bfloat16(f); }
__device__ __forceinline__ float sigmoidf_(float x){ return 1.f/(1.f+expf(-x)); }
__device__ __forceinline__ float siluf_(float x){ return x*sigmoidf_(x); }
__device__ __forceinline__ float softplusf_(float x){ return (x>20.f)? x : log1pf(expf(x)); }

__device__ __forceinline__ unsigned int pack2(float a, float b) {
  unsigned short ua = __builtin_bit_cast(unsigned short, (__bf16)a);
  unsigned short ub = __builtin_bit_cast(unsigned short, (__bf16)b);
  return (unsigned int)ua | ((unsigned int)ub << 16);
}
__device__ __forceinline__ uint4 cvt8(float4 v0, float4 v1) {
  uint4 r;
  r.x = pack2(v0.x, v0.y); r.y = pack2(v0.z, v0.w);
  r.z = pack2(v1.x, v1.y); r.w = pack2(v1.z, v1.w);
  return r;
}

enum EpiKind { EPI_PART=0, EPI_G2=1, EPI_G4=2, EPI_BIAS=3 };

struct KParams {
  const float *uk, *tk_c, *tk_p, *W_in, *b_in, *rW, *rb, *freq, *phase, *kanW;
  const float *W_inproj, *conv_w, *conv_b, *W_x, *W_dt, *dt_bias, *W_delta, *D_skip, *W_out;
  __hip_bfloat16 *Pu, *Xs, *Sz, *Yb, *Acat;
  __hip_bfloat16 *Wip_bf, *Wx_bf, *Wdt128, *Wout_bf;
  float *bc, *Part, *out_hk, *out_w, *out_mask;
};

// ---- weight f32 -> bf16 convert helper ----
__device__ __forceinline__ void cvt_chunk(const float* __restrict__ s,
                                          __hip_bfloat16* __restrict__ d)
{
  float4 v0 = *reinterpret_cast<const float4*>(s);
  float4 v1 = *reinterpret_cast<const float4*>(s + 4);
  *reinterpret_cast<uint4*>(d) = cvt8(v0, v1);
}

// C[m,n] = sum_k A[m,k]*B[n,k], K-contiguous operands (bf16, or f32 with
// on-the-fly cvt when CVTA/CVTB). 256 threads = 4 waves (2x2), wave tile
// 16x32, 16x16x32 bf16 MFMA. BK=128: >=96 B/thread of global loads per
// barrier interval (compiler's vmcnt(0)-before-s_barrier caps in-flight
// bytes at one K-step's issues — BK=64 bf16 gave 48 B and ~726 GB/s, R5;
// BK=128 validated R5->R6 -40us; f32 sources at BK=128 issue 192 B/thread).
template<int BM, int BN, int WMT, int WNT, int EK, bool CVTA, bool CVTB>
__device__ __forceinline__ void gemm_tile(char* smemc, int bxi, int byi, int bzi,
    const void* __restrict__ Ap, const void* __restrict__ Bp,
    float* __restrict__ Coutp, int Ka, int Kb, int kLen, int N, const KParams& p)
{
  static_assert(BM == 32*WMT && BN == 32*WNT, "2x2 wave layout");
  constexpr int BK = 128, SA = 136;             // 272B rows keep 16B align
  constexpr int NA = (BM*BK)/(256*8);
  constexpr int NB = (BN*BK)/(256*8);
  ushort_t* sA = (ushort_t*)smemc;
  ushort_t* sB = (ushort_t*)(smemc + (size_t)2*BM*SA*sizeof(ushort_t));
  const int tid  = threadIdx.x;
  const int wave = tid >> 6, lane = tid & 63;
  const int wm = wave >> 1, wn = wave & 1;
  const int r = lane & 15, q = lane >> 4;
  const int bm = byi * BM, bn = bxi * BN;
  const int kBase = bzi * kLen;
  const int T = kLen / BK;

  uint4 ua[NA], ub[NB];
  float4 fa[NA][2], fb[NB][2];

  auto loadTiles = [&](int k0) {
    #pragma unroll
    for (int c=0;c<NA;++c) {
      int idx = tid*8 + c*2048; int row = idx>>7, kk = idx&127;
      if constexpr (CVTA) {
        const float* s = (const float*)Ap + (size_t)(bm+row)*Ka + k0 + kk;
        fa[c][0] = *reinterpret_cast<const float4*>(s);
        fa[c][1] = *reinterpret_cast<const float4*>(s+4);
      } else {
        ua[c] = *reinterpret_cast<const uint4*>((const __hip_bfloat16*)Ap + (size_t)(bm+row)*Ka + k0 + kk);
      }
    }
    #pragma unroll
    for (int c=0;c<NB;++c) {
      int idx = tid*8 + c*2048; int row = idx>>7, kk = idx&127;
      if constexpr (CVTB) {
        const float* s = (const float*)Bp + (size_t)(bn+row)*Kb + k0 + kk;
        fb[c][0] = *reinterpret_cast<const float4*>(s);
        fb[c][1] = *reinterpret_cast<const float4*>(s+4);
      } else {
        ub[c] = *reinterpret_cast<const uint4*>((const __hip_bfloat16*)Bp + (size_t)(bn+row)*Kb + k0 + kk);
      }
    }
  };
  auto writeTiles = [&](int buf) {
    #pragma unroll
    for (int c=0;c<NA;++c) {
      int idx = tid*8 + c*2048; int row = idx>>7, kk = idx&127;
      uint4 v; if constexpr (CVTA) v = cvt8(fa[c][0], fa[c][1]); else v = ua[c];
      *reinterpret_cast<uint4*>(&sA[buf*(BM*SA) + row*SA + kk]) = v;
    }
    #pragma unroll
    for (int c=0;c<NB;++c) {
      int idx = tid*8 + c*2048; int row = idx>>7, kk = idx&127;
      uint4 v; if constexpr (CVTB) v = cvt8(fb[c][0], fb[c][1]); else v = ub[c];
      *reinterpret_cast<uint4*>(&sB[buf*(BN*SA) + row*SA + kk]) = v;
    }
  };

  f32x4 acc[WMT][WNT];
  #pragma unroll
  for (int i=0;i<WMT;++i)
    #pragma unroll
    for (int j=0;j<WNT;++j) acc[i][j] = (f32x4){0.f,0.f,0.f,0.f};

  loadTiles(kBase);
  writeTiles(0);
  for (int t=0; t<T; ++t) {
    __syncthreads();
    const int cur = t & 1;
    if (t+1 < T) loadTiles(kBase + (t+1)*BK);   // overlaps MFMA below
    #pragma unroll
    for (int ks=0; ks<4; ++ks) {
      bf16x8 af[WMT], bfr[WNT];
      #pragma unroll
      for (int mt=0; mt<WMT; ++mt)
        af[mt] = *reinterpret_cast<const bf16x8*>(&sA[cur*(BM*SA) + (wm*(WMT*16)+mt*16+r)*SA + ks*32 + q*8]);
      #pragma unroll
      for (int nt=0; nt<WNT; ++nt)
        bfr[nt] = *reinterpret_cast<const bf16x8*>(&sB[cur*(BN*SA) + (wn*(WNT*16)+nt*16+r)*SA + ks*32 + q*8]);
      #pragma unroll
      for (int mt=0; mt<WMT; ++mt)
        #pragma unroll
        for (int nt=0; nt<WNT; ++nt)
          acc[mt][nt] = __builtin_amdgcn_mfma_f32_16x16x32_bf16(af[mt], bfr[nt], acc[mt][nt], 0,0,0);
    }
    if (t+1 < T) writeTiles(cur ^ 1);
  }

  #pragma unroll
  for (int mt=0; mt<WMT; ++mt) {
    #pragma unroll
    for (int nt=0; nt<WNT; ++nt) {
      #pragma unroll
      for (int i=0;i<4;++i) {
        int grow = bm + wm*(WMT*16) + mt*16 + q*4 + i;
        int gcol = bn + wn*(WNT*16) + nt*16 + r;
        float v = acc[mt][nt][i];
        if constexpr (EK == EPI_PART) {
          float* P = Coutp + (size_t)bzi * ((size_t)B_*N);
          P[(size_t)grow*N + gcol] = v;
        } else if constexpr (EK == EPI_BIAS) {
          p.Pu[(size_t)grow*N + gcol] = f2bf(v + p.b_in[gcol]);
        } else if constexpr (EK == EPI_G2) {
          if (gcol < DI) {  // x half: conv last tap + silu
            float xc = v * p.conv_w[gcol*DC + (DC-1)] + p.conv_b[gcol];
            p.Xs[(size_t)grow*DI + gcol] = f2bf(siluf_(xc));
          } else {          // z half: silu(z)
            p.Sz[(size_t)grow*DI + (gcol - DI)] = f2bf(siluf_(v));
          }
        }
      }
    }
  }
}

// ---- routing / kan ----

__device__ __forceinline__ void route(float t, const float* rW, const float* rb,
                                      float* w, float* mask, float* wn)
{
  float l[E_];
  float m = -1e30f;
  for (int e=0;e<E_;++e){ l[e] = t*rW[e] + rb[e]; m = fmaxf(m, l[e]); }
  float s = 0.f;
  for (int e=0;e<E_;++e){ w[e] = expf(l[e]-m); s += w[e]; }
  for (int e=0;e<E_;++e) w[e] /= s;
  int i1 = 0;
  for (int e=1;e<E_;++e) if (w[e] > w[i1]) i1 = e;
  int i2 = -1;
  for (int e=0;e<E_;++e) if (e != i1 && (i2 < 0 || w[e] > w[i2])) i2 = e;
  float ssel = w[i1] + w[i2] + 1e-8f;
  for (int e=0;e<E_;++e){
    float mk = (e==i1 || e==i2) ? 1.f : 0.f;
    mask[e] = mk;
    wn[e] = mk * w[e] / ssel;
  }
}

// One job = 4 batch rows, one per wave. kanW dot staged through LDS in 4
// coalesced 32KB j-window chunks (rows padded to 132 floats vs bank stride)
// — R6's 50us uncoalesced-gather straggler fixed this way (R7: -9us dur).
__device__ __forceinline__ void kan_job(char* smemc, int job, const KParams& p)
{
  float* dphi   = (float*)smemc;                // 4 waves x 512 floats = 8 KB
  float* kchunk = dphi + 4*512;                 // 64 rows x 132 floats = 33 KB
  const int tid = threadIdx.x;
  const int wv = tid >> 6, lane = tid & 63;
  const int b = job*4 + wv;
  {
    float t  = p.tk_c[b];
    float tp = p.tk_p[b];
    float w_c[E_], mk_c[E_], wn_c[E_];
    float w_p[E_], mk_p[E_], wn_p[E_];
    route(t,  p.rW, p.rb, w_c, mk_c, wn_c);
    route(tp, p.rW, p.rb, w_p, mk_p, wn_p);
    if (lane < E_) {
      p.out_w[b*E_ + lane]    = w_c[lane];
      p.out_mask[b*E_ + lane] = mk_c[lane];
    }
    float ec = 0.f, epv = 0.f;
    #pragma unroll
    for (int e=0;e<E_;++e) {
      float f  = p.freq[e*DT + lane];
      float ph = p.phase[e*DT + lane];
      ec  += wn_c[e] * sinf(t*f + ph);
      epv += wn_p[e] * sinf(tp*f + ph);
    }
    const float h = 2.f/(G_-1);
    #pragma unroll
    for (int g=0; g<G_; ++g) {
      float gr = -1.f + g*h;
      float a  = (ec - gr)/h;
      float bb = (epv - gr)/h;
      dphi[wv*512 + lane*G_ + g] = expf(-a*a) - expf(-bb*bb);
    }
  }

  float accv = 0.f;
  #pragma unroll
  for (int c=0;c<4;++c) {                       // j-window = 128 floats
    __syncthreads();                            // dphi ready (c=0) / kchunk reuse
    {                                           // stage: 64 rows x 512B, coalesced
      const int rr = tid >> 2, seg = tid & 3;
      const float* src = p.kanW + (size_t)rr*512 + c*128 + seg*32;
      float* dst = kchunk + rr*132 + seg*32;
      #pragma unroll
      for (int i=0;i<8;++i)
        *reinterpret_cast<float4*>(dst + i*4) = *reinterpret_cast<const float4*>(src + i*4);
    }
    __syncthreads();
    const float* kr = kchunk + lane*132;        // lane's output row
    const float* dd = dphi + wv*512 + c*128;
    #pragma unroll
    for (int j=0;j<128;j+=4) {
      float4 kv = *reinterpret_cast<const float4*>(kr + j);
      float4 dv = *reinterpret_cast<const float4*>(dd + j);
      accv += kv.x*dv.x + kv.y*dv.y + kv.z*dv.z + kv.w*dv.w;
    }
  }
  p.Acat[b*128 + 64 + lane] = f2bf(accv);
}

// ---- kernels (one symbol per stage so rocprof top-5 identifies the stage) ----

#define GEMM_SMEM(BM,BN) ((2*(BM)*136 + 2*(BN)*136)*2)

// K1: three disjoint block ranges in ONE launch:
//   ids [0,128)      kan (long pole, first)
//   ids [128,384)    G1 UN-SPLIT (T=8), f32 direct, bias fused -> Pu bf16.
//                    Occupancy during its run comes from the convert blocks.
//   ids [384,3776)   weight converts for later stages (Wip/Wx/Wout/Wdt128) —
//                    G2+ consume them, the kernel boundary is the fence.
__global__ __launch_bounds__(256)
void g1kan_conv_kernel(KParams p)
{
  __shared__ __align__(16) char smem[GEMM_SMEM(32,64)];   // 52224 B
  const int id = blockIdx.x, t = threadIdx.x;
  if (id < 128) {
    kan_job(smem, id, p);
  } else if (id < 384) {
    const int id2 = id - 128;
    const int bxi = id2 & 15, byi = id2 >> 4;
    gemm_tile<32,64,1,2,EPI_BIAS,true,true>(smem, bxi, byi, 0,
        p.uk, p.W_in, nullptr, DM, DM, DM, DM, p);
  } else if (id < 2432) { size_t c = (size_t)(id-384)*256 + t;  cvt_chunk(p.W_inproj + c*8, p.Wip_bf  + c*8); }
  else if (id < 2624)   { size_t c = (size_t)(id-2432)*256 + t; cvt_chunk(p.W_x      + c*8, p.Wx_bf   + c*8); }
  else if (id < 3648)   { size_t c = (size_t)(id-2624)*256 + t; cvt_chunk(p.W_out    + c*8, p.Wout_bf + c*8); }
  else {                  size_t c = (size_t)(id-3648)*256 + t; // [W_dt|W_delta] -> 2048x128
    int row = (int)(c >> 4), col0 = ((int)c & 15)*8;
    const float* s = (col0 < 64) ? (p.W_dt    + (size_t)row*64 + col0)
                                 : (p.W_delta + (size_t)row*64 + (col0-64));
    cvt_chunk(s, p.Wdt128 + (size_t)row*128 + col0);
  }
}

// G2: xz = pu @ W_inproj^T (512x4096x1024), conv+silu / silu fused. 1024 wgs.
__global__ __launch_bounds__(256)
void g2_kernel(KParams p)
{
  __shared__ __align__(16) char smem[GEMM_SMEM(32,64)];
  const int bxi = blockIdx.x & 63, byi = blockIdx.x >> 6;
  gemm_tile<32,64,1,2,EPI_G2,false,false>(smem, bxi, byi, 0, p.Pu, p.Wip_bf, nullptr, DM, DM, DM, 2*DI, p);
}

// G3: x_dbl = xs @ W_x^T (512x192x2048), split-K x8 -> partials. 384 wgs.
__global__ __launch_bounds__(256)
void g3_kernel(KParams p)
{
  __shared__ __align__(16) char smem[GEMM_SMEM(32,64)];
  const int bxi = blockIdx.x % 3, rem = blockIdx.x / 3;
  const int byi = rem & 15, bzi = rem >> 4;
  gemm_tile<32,64,1,2,EPI_PART,false,false>(smem, bxi, byi, bzi, p.Xs, p.Wx_bf, p.Part, DI, DI, 256, 192, p);
}

// G4 with fused R3-reduce prologue (R3-verified path). Grid 256 = 16 M x 16 N
// (BN=128). Phase 1: reduce 8 Part splits for this wg's 32 rows -> dt_r bf16
// (sA cols 0..63) + B/C f32 scratch; kan half from Acat -> sA cols 64..127.
// Phase 2: bc[row] = dot(B,C) in-LDS. Phase 3: stage Wdt128 (pre-converted
// bf16 copy). Phase 4: single-shot K=128 MFMA + softplus/y epilogue.
__global__ __launch_bounds__(256)
void g4_kernel(KParams p)
{
  __shared__ __align__(16) ushort_t sA4[32*136];    // 8704 B
  __shared__ __align__(16) ushort_t sB4[128*136];   // 34816 B
  __shared__ float sBcOut[32];
  float* sBC = (float*)sB4;                         // 32x128 f32 scratch overlay

  const int tid = threadIdx.x;
  const int byi = blockIdx.x & 15, bxi = blockIdx.x >> 4;
  const int bm = byi*32, bn = bxi*128;

  // phase 1: split-K reduce of Part rows [bm,bm+32) x 192 cols (float4 chunks)
  #pragma unroll
  for (int c=0;c<6;++c) {
    int f4id = tid + c*256;                 // 1536 = 32 rows * 48 chunks
    int row = f4id / 48, cq = f4id % 48;
    int col0 = cq*4;
    const float* src = p.Part + (size_t)(bm+row)*192 + col0;
    float4 s = {0.f,0.f,0.f,0.f};
    #pragma unroll
    for (int k=0;k<8;++k) {
      float4 tv = *reinterpret_cast<const float4*>(src + (size_t)k*((size_t)B_*192));
      s.x+=tv.x; s.y+=tv.y; s.z+=tv.z; s.w+=tv.w;
    }
    if (col0 < 64) {          // dt_r -> sA bf16
      uint2 o; o.x = pack2(s.x, s.y); o.y = pack2(s.z, s.w);
      *reinterpret_cast<uint2*>(&sA4[row*136 + col0]) = o;
    } else {                  // B (cols 0..63) | C (cols 64..127) scratch
      *reinterpret_cast<float4*>(&sBC[row*128 + (col0-64)]) = s;
    }
  }
  // kan half of A: Acat[:,64:128] -> sA cols 64..127
  {
    int row = tid >> 3, c0 = (tid & 7)*8;
    uint4 kv = *reinterpret_cast<const uint4*>(p.Acat + (size_t)(bm+row)*128 + 64 + c0);
    *reinterpret_cast<uint4*>(&sA4[row*136 + 64 + c0]) = kv;
  }
  __syncthreads();

  // phase 2: bc[row] = dot(B_row, C_row); 2 lanes per row
  if (tid < 64) {
    int row = tid >> 1, half = tid & 1;
    const float* base = &sBC[row*128 + half*32];
    float a = 0.f;
    #pragma unroll
    for (int j=0;j<8;++j) {
      float4 bv = *reinterpret_cast<const float4*>(base + 4*j);
      float4 cv = *reinterpret_cast<const float4*>(base + 64 + 4*j);
      a += bv.x*cv.x + bv.y*cv.y + bv.z*cv.z + bv.w*cv.w;
    }
    a += __shfl_xor(a, 1);
    if (half == 0) sBcOut[row] = a;
  }
  __syncthreads();

  // phase 3: stage Wdt128 rows [bn,bn+128), K=128 bf16 copy (overwrites sBC)
  #pragma unroll
  for (int c=0;c<8;++c) {
    int e = tid + c*256;                    // 2048 = 128 rows * 16 chunks
    int row = e >> 4, col0 = (e & 15)*8;
    *reinterpret_cast<uint4*>(&sB4[row*136 + col0]) =
        *reinterpret_cast<const uint4*>(p.Wdt128 + (size_t)(bn+row)*128 + col0);
  }
  __syncthreads();

  // phase 4: MFMA, wave tile 16x64 (2x2 waves over 32x128)
  const int wave = tid >> 6, lane = tid & 63;
  const int wm = wave >> 1, wn = wave & 1;
  const int r = lane & 15, q = lane >> 4;
  f32x4 acc[4];
  #pragma unroll
  for (int nt=0;nt<4;++nt) acc[nt] = (f32x4){0.f,0.f,0.f,0.f};
  #pragma unroll
  for (int ks=0;ks<4;++ks) {
    bf16x8 af = *reinterpret_cast<const bf16x8*>(&sA4[(wm*16+r)*136 + ks*32 + q*8]);
    #pragma unroll
    for (int nt=0;nt<4;++nt) {
      bf16x8 bf = *reinterpret_cast<const bf16x8*>(&sB4[(wn*64+nt*16+r)*136 + ks*32 + q*8]);
      acc[nt] = __builtin_amdgcn_mfma_f32_16x16x32_bf16(af, bf, acc[nt], 0,0,0);
    }
  }

  // epilogue: dt = softplus(v + dt_bias); y = (dt*x*bc + D_skip*x)*silu(z)
  #pragma unroll
  for (int nt=0;nt<4;++nt) {
    #pragma unroll
    for (int i=0;i<4;++i) {
      int lrow = wm*16 + q*4 + i;
      int grow = bm + lrow;
      int gcol = bn + wn*64 + nt*16 + r;
      float dt  = softplusf_(acc[nt][i] + p.dt_bias[gcol]);
      float xsv = bf2f(p.Xs[(size_t)grow*DI + gcol]);
      float szv = bf2f(p.Sz[(size_t)grow*DI + gcol]);
      float y = (dt * xsv * sBcOut[lrow] + p.D_skip[gcol] * xsv) * szv;
      p.Yb[(size_t)grow*DI + gcol] = f2bf(y);
    }
  }
}

// G5: hk = y @ W_out^T (512x1024x2048), split-K x4 -> partials. 1024 wgs.
__global__ __launch_bounds__(256)
void g5_kernel(KParams p)
{
  __shared__ __align__(16) char smem[GEMM_SMEM(32,64)];
  const int bxi = blockIdx.x & 15, rem = blockIdx.x >> 4;
  const int byi = rem & 15, bzi = rem >> 4;
  gemm_tile<32,64,1,2,EPI_PART,false,false>(smem, bxi, byi, bzi, p.Yb, p.Wout_bf, p.Part, DI, DI, 512, DM, p);
}

// hk = sum_{s<4} part[s]  (f32 out)
__global__ __launch_bounds__(256)
void reduce_plain_kernel(KParams p)
{
  const int i = blockIdx.x*256 + threadIdx.x;
  const int total = B_*DM/4;
  const float4* pp = (const float4*)p.Part;
  float4 s = pp[i];
  #pragma unroll
  for (int k=1;k<4;++k){ float4 t = pp[i + k*total]; s.x+=t.x; s.y+=t.y; s.z+=t.z; s.w+=t.w; }
  ((float4*)p.out_hk)[i] = s;
}

extern "C" void kernel_launch(void* const* d_in, const int* in_sizes, int n_in,
                              void* d_out, int out_size, void* d_ws, size_t ws_size,
                              hipStream_t stream)
{
  KParams p;
  p.uk       = (const float*)d_in[0];
  p.tk_c     = (const float*)d_in[1];
  p.tk_p     = (const float*)d_in[2];
  p.W_in     = (const float*)d_in[3];
  p.b_in     = (const float*)d_in[4];
  p.rW       = (const float*)d_in[5];
  p.rb       = (const float*)d_in[6];
  p.freq     = (const float*)d_in[7];
  p.phase    = (const float*)d_in[8];
  p.kanW     = (const float*)d_in[9];
  p.W_inproj = (const float*)d_in[10];
  p.conv_w   = (const float*)d_in[11];
  p.conv_b   = (const float*)d_in[12];
  p.W_x      = (const float*)d_in[13];
  p.W_dt     = (const float*)d_in[14];
  p.dt_bias  = (const float*)d_in[15];
  p.W_delta  = (const float*)d_in[16];
  p.D_skip   = (const float*)d_in[18];
  p.W_out    = (const float*)d_in[19];

  char* ws = (char*)d_ws;
  p.Pu     = (__hip_bfloat16*)(ws);                                // 1 MB
  p.Xs     = (__hip_bfloat16*)(ws + (size_t)(1<<20));              // 2 MB
  p.Sz     = (__hip_bfloat16*)(ws + (size_t)3*(1<<20));            // 2 MB
  p.Yb     = (__hip_bfloat16*)(ws + (size_t)5*(1<<20));            // 2 MB
  p.Acat   = (__hip_bfloat16*)(ws + (size_t)7*(1<<20));            // 128 KB
  p.bc     = (float*)         (ws + (size_t)7*(1<<20) + (128<<10));// 2 KB (unused)
  p.Part   = (float*)         (ws + (size_t)8*(1<<20));            // 8 MB
  p.Wip_bf = (__hip_bfloat16*)(ws + (size_t)19*(1<<20));           // 8 MB
  p.Wx_bf  = (__hip_bfloat16*)(ws + (size_t)27*(1<<20));           // 768 KB
  p.Wdt128 = (__hip_bfloat16*)(ws + (size_t)28*(1<<20));           // 512 KB
  p.Wout_bf= (__hip_bfloat16*)(ws + (size_t)29*(1<<20));           // 4 MB

  p.out_hk   = (float*)d_out;
  p.out_w    = p.out_hk + (size_t)B_*DM;
  p.out_mask = p.out_w  + (size_t)B_*E_;

  // K1: kan + G1 (un-split, bias fused) + weight converts, one launch
  g1kan_conv_kernel<<<dim3(3776), 256, 0, stream>>>(p);

  // G2
  g2_kernel<<<dim3(1024), 256, 0, stream>>>(p);

  // G3 (partials) -> fused G4 (reduce + dt GEMM + y)
  g3_kernel<<<dim3(384), 256, 0, stream>>>(p);
  g4_kernel<<<dim3(256), 256, 0, stream>>>(p);

  // G5 + reduce
  g5_kernel<<<dim3(1024), 256, 0, stream>>>(p);
  reduce_plain_kernel<<<dim3(512), 256, 0, stream>>>(p);
}